// Round 8
// baseline (3004.290 us; speedup 1.0000x reference)
//
#include <hip/hip_runtime.h>

typedef unsigned short u16;
typedef __attribute__((ext_vector_type(8))) short short8;
typedef __attribute__((ext_vector_type(4))) float f32x4;

#define B_   1024
#define S_   64
#define E_   100
#define H_   512
#define XW_  256      /* Xs row: x1[128] | x2[128] */
#define WSZG (32 * 3 * 40 * 512)   /* Wswz elems per encoder = 1,966,080 (dedup'd w1) */
#define GS_  (40 * 512)            /* gate stride inside Wswz */

typedef __attribute__((address_space(1))) const unsigned int gu32;
typedef __attribute__((address_space(3))) unsigned int lu32;

__device__ __forceinline__ float bf2f(u16 u) {
    union { unsigned int u; float f; } c; c.u = ((unsigned int)u) << 16; return c.f;
}
__device__ __forceinline__ u16 f2bf(float f) {
    union { float f; unsigned int u; } c; c.f = f;
    unsigned int r = c.u + 0x7fffu + ((c.u >> 16) & 1u);
    return (u16)(r >> 16);
}
__device__ __forceinline__ f32x4 mfma16(short8 a, short8 b, f32x4 c) {
    return __builtin_amdgcn_mfma_f32_16x16x32_bf16(a, b, c, 0, 0, 0);
}

// ---------- embedding gather -> bf16 hi/lo pair planes, zero-padded to 128 --
__global__ __launch_bounds__(256) void gather_kernel(
    const int* __restrict__ tok, const float* __restrict__ emb, u16* __restrict__ xs)
{
    int tid = threadIdx.x;
    int hw  = tid & 31;
    int rowid = blockIdx.x * 8 + (tid >> 5);      // rowid = t*1024 + b
    int t = rowid >> 10, b = rowid & 1023;
    int token = tok[b * S_ + t];
    const float* src = emb + (long)token * E_;
    u16* dst = xs + (long)rowid * XW_;
    int c0 = hw * 4;
    u16 a1[4], a2[4];
    #pragma unroll
    for (int j = 0; j < 4; ++j) {
        int c = c0 + j;
        float v = (c < E_) ? src[c] : 0.f;
        u16 h = f2bf(v);
        a1[j] = h;
        a2[j] = f2bf(v - bf2f(h));
    }
    uint2 p1, p2;
    p1.x = (unsigned)a1[0] | ((unsigned)a1[1] << 16);
    p1.y = (unsigned)a1[2] | ((unsigned)a1[3] << 16);
    p2.x = (unsigned)a2[0] | ((unsigned)a2[1] << 16);
    p2.y = (unsigned)a2[2] | ((unsigned)a2[3] << 16);
    *(uint2*)(dst + c0)       = p1;
    *(uint2*)(dst + 128 + c0) = p2;
}

// ---------- weight repack into MFMA-fragment order, w1 stored ONCE ----------
// Wswz[ht(32)][gate(3)][ks(40)][lane(64)][8] per encoder.
// ks 0-3: x w1 | ks 4-7: x w2 | ks 8-23: h w1 | ks 24-39: h w2.
__global__ __launch_bounds__(256) void repack_swz(
    const float* __restrict__ wih, const float* __restrict__ whh, u16* __restrict__ out)
{
    long idx = (long)blockIdx.x * 256 + threadIdx.x;   // over WSZG
    int jj   = idx & 7;
    int lane = (idx >> 3) & 63;
    int q9   = (int)(idx >> 9);
    int ks   = q9 % 40;
    int q    = q9 / 40;
    int gate = q % 3;
    int ht   = q / 3;
    int n   = ht * 16 + (lane & 15);
    int ck  = (lane >> 4) * 8 + jj;       // 0..31 within chunk
    int row = gate * H_ + n;
    float w; int lo;
    if (ks < 8) {
        int kk = (ks & 3) * 32 + ck;
        if (kk >= E_) { out[idx] = 0; return; }
        w = wih[row * E_ + kk];
        lo = (ks >> 2);                   // 0=hi(w1), 1=lo(w2)
    } else {
        int rel = ks - 8;
        int kk  = (rel & 15) * 32 + ck;
        w = whh[row * H_ + kk];
        lo = (rel >> 4);
    }
    u16 h = f2bf(w);
    if (lo) h = f2bf(w - bf2f(h));
    out[idx] = h;
}

__global__ __launch_bounds__(256) void repack_lin(
    const float* __restrict__ lw, u16* __restrict__ l1, u16* __restrict__ l2)
{
    int i = blockIdx.x * 256 + threadIdx.x;       // over 512*512
    float w = lw[i];
    u16 h = f2bf(w);
    l1[i] = h;
    l2[i] = f2bf(w - bf2f(h));
}

// ---------- one GRU time step ------------------------------------------------
// R12: exact R4 champion (2120us) + NT cache policy on the STREAMING accesses:
// x/h staging gload_lds carry aux=NT (no L2 allocate), epilogue h RMW uses
// nontemporal load/store. Weights keep default caching -> per-XCD 1.47 MB
// weight set stays L2-resident instead of being evicted by the 15 MB/step
// h/x stream (R2/R6 FETCH showed ~38 MB/step weight refetch from L3).
struct BiasPtrs { const float* bih[3]; const float* bhh[3]; };

__global__ __launch_bounds__(256, 3) void gru_step(
    const u16* __restrict__ xs,      // [3][64][1024][256]
    const u16* __restrict__ wswz,    // [3][WSZG]
    BiasPtrs bp,
    const u16* __restrict__ h1_in, const u16* __restrict__ h2_in,   // [3][1024][512]
    u16* __restrict__ h1_out, u16* __restrict__ h2_out,
    int t)
{
    __shared__ __attribute__((aligned(16))) u16 As[2][2][64 * 64];
    const int tid = threadIdx.x;
    const int lane = tid & 63;
    const int wid = tid >> 6;
    const int kh = tid >> 7;          // K-half  (0,1)
    const int nh = (tid >> 6) & 1;    // ht      (0,1)
    const int l15 = lane & 15, l4 = lane >> 4;
    const int htp = blockIdx.x;       // 0..15  (x-fastest => XCD-pinned weights)
    const int m0  = blockIdx.y * 64;
    const int g   = blockIdx.z;
    const int ht  = htp * 2 + nh;

    const u16* wg  = wswz + (long)g * WSZG + (long)ht * (3 * GS_) + lane * 8;
    const u16* xb  = xs + ((long)(g * S_ + t) * B_ + m0) * XW_;
    const u16* hb1 = h1_in + ((long)g * B_ + m0) * H_;
    const u16* hb2 = h2_in + ((long)g * B_ + m0) * H_;

    f32x4 zero = {0.f, 0.f, 0.f, 0.f};
    f32x4 acc_r[4]  = {zero, zero, zero, zero};
    f32x4 acc_z[4]  = {zero, zero, zero, zero};
    f32x4 acc_ni[4] = {zero, zero, zero, zero};
    f32x4 acc_nh[4] = {zero, zero, zero, zero};

    // stage 16 KB: slot0 <- s0 tile, slot1 <- s1 tile (64 rows x 64 cols).
    // Each wave: 4 segments of 1 KB (8 rows). LDS dest linear; global source
    // pre-swizzled: lane l -> row rblk*8+(l>>3), logical chunk (l&7)^((l>>3)&7).
    // aux=2 (NT): streaming data must not evict L2-resident weights.
    auto stage_async = [&](int buf, const u16* s0, const u16* s1, int stride) {
        #pragma unroll
        for (int i = 0; i < 4; ++i) {
            int seg  = wid * 4 + i;            // 0..15
            int slot = seg >> 3;
            int rblk = seg & 7;
            const u16* src = slot ? s1 : s0;
            int row = rblk * 8 + (lane >> 3);
            int ch  = (lane & 7) ^ ((lane >> 3) & 7);
            const u16* gp = src + (long)row * stride + ch * 8;
            u16* lp = &As[buf][slot][rblk * 8 * 64];
            __builtin_amdgcn_global_load_lds((gu32*)gp, (lu32*)lp, 16, 0, 2);
        }
    };
    // swizzled A-fragment read: row r=q*16+l15, logical chunk ksl*4+l4
    auto ldA = [&](const u16* sp, int ksl, int q) -> short8 {
        int r = q * 16 + l15;
        int p = ((ksl << 2) + l4) ^ (l15 & 7);
        return *(const short8*)(&sp[r * 64 + p * 8]);
    };
    auto consume_dual = [&](int buf, const u16* b1, const u16* b2, f32x4* accn) {
        const u16* sp = &As[buf][kh][0];
        #pragma unroll
        for (int ksl = 0; ksl < 2; ++ksl) {
            short8 br1 = *(const short8*)(b1 + ksl * 512);
            short8 bz1 = *(const short8*)(b1 + GS_ + ksl * 512);
            short8 bn1 = *(const short8*)(b1 + 2 * GS_ + ksl * 512);
            short8 br2 = *(const short8*)(b2 + ksl * 512);
            short8 bz2 = *(const short8*)(b2 + GS_ + ksl * 512);
            short8 bn2 = *(const short8*)(b2 + 2 * GS_ + ksl * 512);
            short8 a[4];
            #pragma unroll
            for (int q = 0; q < 4; ++q) a[q] = ldA(sp, ksl, q);
            #pragma unroll
            for (int q = 0; q < 4; ++q) {
                acc_r[q] = mfma16(a[q], br1, acc_r[q]);
                acc_z[q] = mfma16(a[q], bz1, acc_z[q]);
                accn[q]  = mfma16(a[q], bn1, accn[q]);
                acc_r[q] = mfma16(a[q], br2, acc_r[q]);
                acc_z[q] = mfma16(a[q], bz2, acc_z[q]);
                accn[q]  = mfma16(a[q], bn2, accn[q]);
            }
        }
    };
    auto consume_single = [&](int buf, const u16* b1, f32x4* accn) {
        const u16* sp = &As[buf][kh][0];
        #pragma unroll
        for (int ksl = 0; ksl < 2; ++ksl) {
            short8 br1 = *(const short8*)(b1 + ksl * 512);
            short8 bz1 = *(const short8*)(b1 + GS_ + ksl * 512);
            short8 bn1 = *(const short8*)(b1 + 2 * GS_ + ksl * 512);
            short8 a[4];
            #pragma unroll
            for (int q = 0; q < 4; ++q) a[q] = ldA(sp, ksl, q);
            #pragma unroll
            for (int q = 0; q < 4; ++q) {
                acc_r[q] = mfma16(a[q], br1, acc_r[q]);
                acc_z[q] = mfma16(a[q], bz1, acc_z[q]);
                accn[q]  = mfma16(a[q], bn1, accn[q]);
            }
        }
    };

    // ---- prologue: stage X1 into buf 0 ----
    stage_async(0, xb, xb + 64, XW_);
    // P0: X1 dual (w1x + w2x); prefetch X2
    __syncthreads();
    stage_async(1, xb + 128, xb + 192, XW_);
    consume_dual(0, wg + (2 * kh) * 512, wg + (4 + 2 * kh) * 512, acc_ni);
    // P1: X2 single (same w1x addresses, L2-hot); prefetch H1 i=0
    __syncthreads();
    stage_async(0, hb1, hb1 + 4 * 64, H_);
    consume_single(1, wg + (2 * kh) * 512, acc_ni);
    // P2: H1 i=0 dual; prefetch H1 i=1
    __syncthreads();
    stage_async(1, hb1 + 1 * 64, hb1 + 5 * 64, H_);
    consume_dual(0, wg + (8 + 8 * kh + 0) * 512, wg + (24 + 8 * kh + 0) * 512, acc_nh);
    // P3: H1 i=1 dual; prefetch H1 i=2
    __syncthreads();
    stage_async(0, hb1 + 2 * 64, hb1 + 6 * 64, H_);
    consume_dual(1, wg + (8 + 8 * kh + 2) * 512, wg + (24 + 8 * kh + 2) * 512, acc_nh);
    // P4: H1 i=2 dual; prefetch H1 i=3
    __syncthreads();
    stage_async(1, hb1 + 3 * 64, hb1 + 7 * 64, H_);
    consume_dual(0, wg + (8 + 8 * kh + 4) * 512, wg + (24 + 8 * kh + 4) * 512, acc_nh);
    // P5: H1 i=3 dual; prefetch H2 i=0
    __syncthreads();
    stage_async(0, hb2, hb2 + 4 * 64, H_);
    consume_dual(1, wg + (8 + 8 * kh + 6) * 512, wg + (24 + 8 * kh + 6) * 512, acc_nh);
    // P6: H2 i=0 single (same h-w1 addresses); prefetch H2 i=1
    __syncthreads();
    stage_async(1, hb2 + 1 * 64, hb2 + 5 * 64, H_);
    consume_single(0, wg + (8 + 8 * kh + 0) * 512, acc_nh);
    // P7: H2 i=1 single; prefetch H2 i=2
    __syncthreads();
    stage_async(0, hb2 + 2 * 64, hb2 + 6 * 64, H_);
    consume_single(1, wg + (8 + 8 * kh + 2) * 512, acc_nh);
    // P8: H2 i=2 single; prefetch H2 i=3
    __syncthreads();
    stage_async(1, hb2 + 3 * 64, hb2 + 7 * 64, H_);
    consume_single(0, wg + (8 + 8 * kh + 4) * 512, acc_nh);
    // P9: H2 i=3 single (no prefetch)
    __syncthreads();
    consume_single(1, wg + (8 + 8 * kh + 6) * 512, acc_nh);

    // ---- K-half reduction through LDS (first 16 KB = As[0], disjoint from
    // As[1] that P9 stragglers still read). XOR chunk swizzle: conflict-free.
    f32x4* rp = (f32x4*)As;
    const int rbase = (nh * 64 + lane) * 8;
    const int rxor  = lane & 7;
    if (kh == 1) {
        #pragma unroll
        for (int q = 0; q < 4; ++q) {
            rp[rbase + (q ^ rxor)]       = acc_r[q];
            rp[rbase + ((4 + q) ^ rxor)] = acc_z[q];
        }
    }
    __syncthreads();
    if (kh == 0) {
        #pragma unroll
        for (int q = 0; q < 4; ++q) {
            acc_r[q] += rp[rbase + (q ^ rxor)];
            acc_z[q] += rp[rbase + ((4 + q) ^ rxor)];
        }
    }
    __syncthreads();
    if (kh == 1) {
        #pragma unroll
        for (int q = 0; q < 4; ++q) {
            rp[rbase + (q ^ rxor)]       = acc_ni[q];
            rp[rbase + ((4 + q) ^ rxor)] = acc_nh[q];
        }
    }
    __syncthreads();
    if (kh == 0) {
        #pragma unroll
        for (int q = 0; q < 4; ++q) {
            acc_ni[q] += rp[rbase + (q ^ rxor)];
            acc_nh[q] += rp[rbase + ((4 + q) ^ rxor)];
        }

        // ---- GRU pointwise epilogue (f32); NT load/store for h RMW --------
        int hc = ht * 16 + l15;
        const float* bih = bp.bih[g];
        const float* bhh = bp.bhh[g];
        float b_ir = bih[hc],          b_hr = bhh[hc];
        float b_iz = bih[H_ + hc],     b_hz = bhh[H_ + hc];
        float b_in = bih[2 * H_ + hc], b_hn = bhh[2 * H_ + hc];
        #pragma unroll
        for (int mt = 0; mt < 4; ++mt) {
            #pragma unroll
            for (int i = 0; i < 4; ++i) {
                int m = m0 + mt * 16 + l4 * 4 + i;
                long idx = ((long)g * B_ + m) * H_ + hc;
                float pr = acc_r[mt][i] + b_ir + b_hr;
                float pz = acc_z[mt][i] + b_iz + b_hz;
                float vi = acc_ni[mt][i] + b_in;
                float vh = acc_nh[mt][i] + b_hn;
                float r = 1.f / (1.f + __expf(-pr));
                float z = 1.f / (1.f + __expf(-pz));
                float n = tanhf(vi + r * vh);
                float hold = bf2f(__builtin_nontemporal_load(h1_in + idx))
                           + bf2f(__builtin_nontemporal_load(h2_in + idx));
                float hnew = (1.f - z) * n + z * hold;
                u16 hh = f2bf(hnew);
                __builtin_nontemporal_store(hh, h1_out + idx);
                __builtin_nontemporal_store(f2bf(hnew - bf2f(hh)), h2_out + idx);
            }
        }
    }
}

// ---------- qc = 0.5*(eq+ec) from bf16 pairs, split into bf16 pair ----------
__global__ __launch_bounds__(256) void qc_kernel(
    const u16* __restrict__ h1, const u16* __restrict__ h2,
    u16* __restrict__ q1, u16* __restrict__ q2)
{
    int i = blockIdx.x * 256 + threadIdx.x;       // over 1024*512
    float eq = bf2f(h1[i]) + bf2f(h2[i]);
    float ec = bf2f(h1[B_ * H_ + i]) + bf2f(h2[B_ * H_ + i]);
    float q = 0.5f * (eq + ec);
    u16 h = f2bf(q);
    q1[i] = h;
    q2[i] = f2bf(q - bf2f(h));
}

// ---------- generic NT GEMM with per-chunk source pointers ------------------
struct GArgs { const u16* a[24]; const u16* b[24]; };

__global__ __launch_bounds__(256) void gemm_nt(
    GArgs ga, int nch, int astr, int bstr,
    const float* __restrict__ bias, float* __restrict__ outf,
    u16* __restrict__ ohi, u16* __restrict__ olo, int ldc, int mode)
{
    __shared__ __attribute__((aligned(16))) u16 As[64 * 72];
    __shared__ __attribute__((aligned(16))) u16 Bs[64 * 72];
    const int tid = threadIdx.x;
    const int w = tid >> 6, lane = tid & 63;
    const int l15 = lane & 15, l4 = lane >> 4;
    const int m0 = blockIdx.x * 64, n0 = blockIdx.y * 64;

    f32x4 zero = {0.f, 0.f, 0.f, 0.f};
    f32x4 acc[4] = {zero, zero, zero, zero};

    for (int c = 0; c < nch; ++c) {
        int row = tid >> 2, seg = tid & 3;
        const u16* sa = ga.a[c] + (long)(m0 + row) * astr + seg * 16;
        *(uint4*)(&As[row * 72 + seg * 16])     = *(const uint4*)(sa);
        *(uint4*)(&As[row * 72 + seg * 16 + 8]) = *(const uint4*)(sa + 8);
        const u16* sb = ga.b[c] + (long)(n0 + row) * bstr + seg * 16;
        *(uint4*)(&Bs[row * 72 + seg * 16])     = *(const uint4*)(sb);
        *(uint4*)(&Bs[row * 72 + seg * 16 + 8]) = *(const uint4*)(sb + 8);
        __syncthreads();
        #pragma unroll
        for (int ks = 0; ks < 2; ++ks) {
            short8 bfrag = *(const short8*)(&Bs[(w * 16 + l15) * 72 + ks * 32 + l4 * 8]);
            #pragma unroll
            for (int rt = 0; rt < 4; ++rt) {
                short8 a = *(const short8*)(&As[(rt * 16 + l15) * 72 + ks * 32 + l4 * 8]);
                acc[rt] = mfma16(a, bfrag, acc[rt]);
            }
        }
        __syncthreads();
    }

    int n = n0 + w * 16 + l15;
    float bv = bias ? bias[n] : 0.f;
    #pragma unroll
    for (int rt = 0; rt < 4; ++rt) {
        #pragma unroll
        for (int i = 0; i < 4; ++i) {
            int m = m0 + rt * 16 + l4 * 4 + i;
            float v = acc[rt][i] + bv;
            if (mode == 0) {
                outf[(long)m * ldc + n] = v;
            } else {
                u16 h = f2bf(v);
                ohi[(long)m * ldc + n] = h;
                olo[(long)m * ldc + n] = f2bf(v - bf2f(h));
            }
        }
    }
}

// ---------- row softmax (1024 wide), f32 in/out -----------------------------
__global__ __launch_bounds__(256) void softmax_kernel(
    const float* __restrict__ lg, float* __restrict__ out)
{
    __shared__ float red[256];
    int row = blockIdx.x, tid = threadIdx.x;
    const float* src = lg + (long)row * 1024;
    float x[4];
    float mx = -1e30f;
    #pragma unroll
    for (int i = 0; i < 4; ++i) { x[i] = src[tid + 256 * i]; mx = fmaxf(mx, x[i]); }
    red[tid] = mx; __syncthreads();
    for (int s = 128; s > 0; s >>= 1) { if (tid < s) red[tid] = fmaxf(red[tid], red[tid + s]); __syncthreads(); }
    mx = red[0]; __syncthreads();
    float sm = 0.f;
    #pragma unroll
    for (int i = 0; i < 4; ++i) { x[i] = __expf(x[i] - mx); sm += x[i]; }
    red[tid] = sm; __syncthreads();
    for (int s = 128; s > 0; s >>= 1) { if (tid < s) red[tid] += red[tid + s]; __syncthreads(); }
    float inv = 1.f / red[0];
    float* dst = out + (long)row * 1024;
    #pragma unroll
    for (int i = 0; i < 4; ++i) dst[tid + 256 * i] = x[i] * inv;
}

// ---------------------------------------------------------------------------
extern "C" void kernel_launch(void* const* d_in, const int* in_sizes, int n_in,
                              void* d_out, int out_size, void* d_ws, size_t ws_size,
                              hipStream_t stream)
{
    const int* tok[3] = {(const int*)d_in[0], (const int*)d_in[1], (const int*)d_in[2]};
    const float *emb[3], *wih[3], *whh[3], *bih[3], *bhh[3];
    for (int g = 0; g < 3; ++g) {
        emb[g] = (const float*)d_in[3 + 5 * g];
        wih[g] = (const float*)d_in[4 + 5 * g];
        whh[g] = (const float*)d_in[5 + 5 * g];
        bih[g] = (const float*)d_in[6 + 5 * g];
        bhh[g] = (const float*)d_in[7 + 5 * g];
    }
    const float* lin_w = (const float*)d_in[18];
    const float* lin_b = (const float*)d_in[19];

    char* ws = (char*)d_ws;
    size_t off = 0;
    auto alloc = [&](size_t bytes) { void* p = ws + off; off += (bytes + 255) & ~255ull; return p; };

    const size_t BH  = (size_t)B_ * H_;           // 524288
    const size_t PRB = 3 * BH * 2;                // bf16 plane bytes (3.1 MB)
    const size_t PING = 2 * PRB;                  // h1+h2 per ping

    u16*   Xs   = (u16*)alloc(3ll * S_ * B_ * XW_ * 2);     // 100.7 MB
    u16*   Wswz = (u16*)alloc(3ll * WSZG * 2);              // 11.8 MB
    u16*   LW1  = (u16*)alloc((size_t)H_ * H_ * 2);
    u16*   LW2  = (u16*)alloc((size_t)H_ * H_ * 2);
    char*  HB   = (char*)alloc(2 * PING);                   // 12.6 MB
    u16*   QC1  = (u16*)alloc(BH * 2);
    u16*   QC2  = (u16*)alloc(BH * 2);
    u16*   EQ1  = (u16*)alloc(BH * 2);
    u16*   EQ2  = (u16*)alloc(BH * 2);
    float* LG   = (float*)alloc(3ll * B_ * B_ * 4);         // 12.6 MB

    u16* H1[2]; u16* H2[2];
    for (int i = 0; i < 2; ++i) {
        char* pb = HB + (size_t)i * PING;
        H1[i] = (u16*)pb;
        H2[i] = (u16*)(pb + PRB);
    }

    hipMemsetAsync(HB, 0, PING, stream);   // zero h0 (ping 0: both planes)

    for (int g = 0; g < 3; ++g) {
        gather_kernel<<<dim3(S_ * B_ / 8), 256, 0, stream>>>(tok[g], emb[g], Xs + (size_t)g * S_ * B_ * XW_);
        repack_swz<<<dim3(WSZG / 256), 256, 0, stream>>>(wih[g], whh[g], Wswz + (size_t)g * WSZG);
    }
    repack_lin<<<dim3(H_ * H_ / 256), 256, 0, stream>>>(lin_w, LW1, LW2);

    BiasPtrs bp;
    for (int g = 0; g < 3; ++g) { bp.bih[g] = bih[g]; bp.bhh[g] = bhh[g]; }

    int p = 0;
    for (int t = S_ - 1; t >= 0; --t) {
        gru_step<<<dim3(16, 16, 3), 256, 0, stream>>>(Xs, Wswz, bp,
            H1[p], H2[p], H1[1 - p], H2[1 - p], t);
        p ^= 1;
    }
    const u16* H1F = H1[p];
    const u16* H2F = H2[p];

    qc_kernel<<<dim3(BH / 256), 256, 0, stream>>>(H1F, H2F, QC1, QC2);

    // eqc = qc @ lin_w.T + lin_b : q1w1 + q2w1 + q1w2 (24 chunks over K=512)
    GArgs ga;
    for (int c = 0; c < 8; ++c)   { ga.a[c] = QC1 + c * 64;        ga.b[c] = LW1 + c * 64; }
    for (int c = 8; c < 16; ++c)  { ga.a[c] = QC2 + (c - 8) * 64;  ga.b[c] = LW1 + (c - 8) * 64; }
    for (int c = 16; c < 24; ++c) { ga.a[c] = QC1 + (c - 16) * 64; ga.b[c] = LW2 + (c - 16) * 64; }
    gemm_nt<<<dim3(16, 8), 256, 0, stream>>>(ga, 24, H_, H_, lin_b, nullptr, EQ1, EQ2, H_, 1);

    // sims: logits = X @ er.T via a1b1 + a2b1 + a1b2
    const u16* R1 = H1F + 2 * BH;
    const u16* R2 = H2F + 2 * BH;
    for (int g = 0; g < 3; ++g) {
        const u16 *A1, *A2;
        if (g == 0)      { A1 = H1F;      A2 = H2F; }
        else if (g == 1) { A1 = H1F + BH; A2 = H2F + BH; }
        else             { A1 = EQ1;      A2 = EQ2; }
        GArgs gs;
        for (int c = 0; c < 8; ++c)   { gs.a[c] = A1 + c * 64;        gs.b[c] = R1 + c * 64; }
        for (int c = 8; c < 16; ++c)  { gs.a[c] = A2 + (c - 8) * 64;  gs.b[c] = R1 + (c - 8) * 64; }
        for (int c = 16; c < 24; ++c) { gs.a[c] = A1 + (c - 16) * 64; gs.b[c] = R2 + (c - 16) * 64; }
        gemm_nt<<<dim3(16, 16), 256, 0, stream>>>(gs, 24, H_, H_, nullptr,
            LG + (size_t)g * B_ * B_, nullptr, nullptr, B_, 0);
    }

    softmax_kernel<<<dim3(3 * B_), 256, 0, stream>>>(LG, (float*)d_out);
}

// Round 9
// 2705.345 us; speedup vs baseline: 1.1105x; 1.1105x over previous
//
#include <hip/hip_runtime.h>

typedef unsigned short u16;
typedef __attribute__((ext_vector_type(8))) short short8;
typedef __attribute__((ext_vector_type(4))) float f32x4;

#define B_   1024
#define S_   64
#define E_   100
#define H_   512
#define XW_  256      /* Xs row: x1[128] | x2[128] */
#define WSZG (32 * 3 * 40 * 512)   /* Wswz elems per encoder = 1,966,080 (dedup'd w1) */
#define GS_  (40 * 512)            /* gate stride inside Wswz */

typedef __attribute__((address_space(1))) const unsigned int gu32;
typedef __attribute__((address_space(3))) unsigned int lu32;

__device__ __forceinline__ float bf2f(u16 u) {
    union { unsigned int u; float f; } c; c.u = ((unsigned int)u) << 16; return c.f;
}
__device__ __forceinline__ u16 f2bf(float f) {
    union { float f; unsigned int u; } c; c.f = f;
    unsigned int r = c.u + 0x7fffu + ((c.u >> 16) & 1u);
    return (u16)(r >> 16);
}
__device__ __forceinline__ f32x4 mfma16(short8 a, short8 b, f32x4 c) {
    return __builtin_amdgcn_mfma_f32_16x16x32_bf16(a, b, c, 0, 0, 0);
}

// ---------- embedding gather -> bf16 hi/lo pair planes, zero-padded to 128 --
__global__ __launch_bounds__(256) void gather_kernel(
    const int* __restrict__ tok, const float* __restrict__ emb, u16* __restrict__ xs)
{
    int tid = threadIdx.x;
    int hw  = tid & 31;
    int rowid = blockIdx.x * 8 + (tid >> 5);      // rowid = t*1024 + b
    int t = rowid >> 10, b = rowid & 1023;
    int token = tok[b * S_ + t];
    const float* src = emb + (long)token * E_;
    u16* dst = xs + (long)rowid * XW_;
    int c0 = hw * 4;
    u16 a1[4], a2[4];
    #pragma unroll
    for (int j = 0; j < 4; ++j) {
        int c = c0 + j;
        float v = (c < E_) ? src[c] : 0.f;
        u16 h = f2bf(v);
        a1[j] = h;
        a2[j] = f2bf(v - bf2f(h));
    }
    uint2 p1, p2;
    p1.x = (unsigned)a1[0] | ((unsigned)a1[1] << 16);
    p1.y = (unsigned)a1[2] | ((unsigned)a1[3] << 16);
    p2.x = (unsigned)a2[0] | ((unsigned)a2[1] << 16);
    p2.y = (unsigned)a2[2] | ((unsigned)a2[3] << 16);
    *(uint2*)(dst + c0)       = p1;
    *(uint2*)(dst + 128 + c0) = p2;
}

// ---------- weight repack into MFMA-fragment order, w1 stored ONCE ----------
// Wswz[ht(32)][gate(3)][ks(40)][lane(64)][8] per encoder.
// ks 0-3: x w1 | ks 4-7: x w2 | ks 8-23: h w1 | ks 24-39: h w2.
__global__ __launch_bounds__(256) void repack_swz(
    const float* __restrict__ wih, const float* __restrict__ whh, u16* __restrict__ out)
{
    long idx = (long)blockIdx.x * 256 + threadIdx.x;   // over WSZG
    int jj   = idx & 7;
    int lane = (idx >> 3) & 63;
    int q9   = (int)(idx >> 9);
    int ks   = q9 % 40;
    int q    = q9 / 40;
    int gate = q % 3;
    int ht   = q / 3;
    int n   = ht * 16 + (lane & 15);
    int ck  = (lane >> 4) * 8 + jj;       // 0..31 within chunk
    int row = gate * H_ + n;
    float w; int lo;
    if (ks < 8) {
        int kk = (ks & 3) * 32 + ck;
        if (kk >= E_) { out[idx] = 0; return; }
        w = wih[row * E_ + kk];
        lo = (ks >> 2);                   // 0=hi(w1), 1=lo(w2)
    } else {
        int rel = ks - 8;
        int kk  = (rel & 15) * 32 + ck;
        w = whh[row * H_ + kk];
        lo = (rel >> 4);
    }
    u16 h = f2bf(w);
    if (lo) h = f2bf(w - bf2f(h));
    out[idx] = h;
}

__global__ __launch_bounds__(256) void repack_lin(
    const float* __restrict__ lw, u16* __restrict__ l1, u16* __restrict__ l2)
{
    int i = blockIdx.x * 256 + threadIdx.x;       // over 512*512
    float w = lw[i];
    u16 h = f2bf(w);
    l1[i] = h;
    l2[i] = f2bf(w - bf2f(h));
}

// ---------- one GRU time step ------------------------------------------------
// R13: R4 champion structure with m-block 128 (grid 16x8x3 = 384 blocks).
// Each block's 491 KB weight read amortizes over 2x batch rows -> weight L2
// traffic halves (377 -> 188 MB/step); per-phase MFMA density doubles against
// the same B-fragment loads. LDS 64 KB (2 blocks/CU), consume in two 4-tile
// half-batches to bound live A-fragments.
struct BiasPtrs { const float* bih[3]; const float* bhh[3]; };

__global__ __launch_bounds__(256, 2) void gru_step(
    const u16* __restrict__ xs,      // [3][64][1024][256]
    const u16* __restrict__ wswz,    // [3][WSZG]
    BiasPtrs bp,
    const u16* __restrict__ h1_in, const u16* __restrict__ h2_in,   // [3][1024][512]
    u16* __restrict__ h1_out, u16* __restrict__ h2_out,
    int t)
{
    __shared__ __attribute__((aligned(16))) u16 As[2][2][128 * 64];  // 64 KB
    const int tid = threadIdx.x;
    const int lane = tid & 63;
    const int wid = tid >> 6;
    const int kh = tid >> 7;          // K-half  (0,1)
    const int nh = (tid >> 6) & 1;    // ht      (0,1)
    const int l15 = lane & 15, l4 = lane >> 4;
    const int htp = blockIdx.x;       // 0..15  (x-fastest => XCD-pinned weights)
    const int m0  = blockIdx.y * 128;
    const int g   = blockIdx.z;
    const int ht  = htp * 2 + nh;

    const u16* wg  = wswz + (long)g * WSZG + (long)ht * (3 * GS_) + lane * 8;
    const u16* xb  = xs + ((long)(g * S_ + t) * B_ + m0) * XW_;
    const u16* hb1 = h1_in + ((long)g * B_ + m0) * H_;
    const u16* hb2 = h2_in + ((long)g * B_ + m0) * H_;

    f32x4 zero = {0.f, 0.f, 0.f, 0.f};
    f32x4 acc_r[8]  = {zero, zero, zero, zero, zero, zero, zero, zero};
    f32x4 acc_z[8]  = {zero, zero, zero, zero, zero, zero, zero, zero};
    f32x4 acc_ni[8] = {zero, zero, zero, zero, zero, zero, zero, zero};
    f32x4 acc_nh[8] = {zero, zero, zero, zero, zero, zero, zero, zero};

    // stage 32 KB: slot0 <- s0 tile, slot1 <- s1 tile (128 rows x 64 cols).
    // Each wave: 8 segments of 1 KB (8 rows). LDS dest linear; global source
    // pre-swizzled: lane l -> row rblk*8+(l>>3), logical chunk (l&7)^((l>>3)&7).
    auto stage_async = [&](int buf, const u16* s0, const u16* s1, int stride) {
        #pragma unroll
        for (int i = 0; i < 8; ++i) {
            int seg  = wid * 8 + i;            // 0..31
            int slot = seg >> 4;
            int rblk = seg & 15;
            const u16* src = slot ? s1 : s0;
            int row = rblk * 8 + (lane >> 3);
            int ch  = (lane & 7) ^ ((lane >> 3) & 7);
            const u16* gp = src + (long)row * stride + ch * 8;
            u16* lp = &As[buf][slot][rblk * 8 * 64];
            __builtin_amdgcn_global_load_lds((gu32*)gp, (lu32*)lp, 16, 0, 0);
        }
    };
    // swizzled A-fragment read: row r=q*16+l15, logical chunk ksl*4+l4
    auto ldA = [&](const u16* sp, int ksl, int q) -> short8 {
        int r = q * 16 + l15;
        int p = ((ksl << 2) + l4) ^ (l15 & 7);
        return *(const short8*)(&sp[r * 64 + p * 8]);
    };
    auto consume_dual = [&](int buf, const u16* b1, const u16* b2, f32x4* accn) {
        const u16* sp = &As[buf][kh][0];
        #pragma unroll
        for (int ksl = 0; ksl < 2; ++ksl) {
            short8 br1 = *(const short8*)(b1 + ksl * 512);
            short8 bz1 = *(const short8*)(b1 + GS_ + ksl * 512);
            short8 bn1 = *(const short8*)(b1 + 2 * GS_ + ksl * 512);
            short8 br2 = *(const short8*)(b2 + ksl * 512);
            short8 bz2 = *(const short8*)(b2 + GS_ + ksl * 512);
            short8 bn2 = *(const short8*)(b2 + 2 * GS_ + ksl * 512);
            #pragma unroll
            for (int half = 0; half < 2; ++half) {
                short8 a[4];
                #pragma unroll
                for (int q = 0; q < 4; ++q) a[q] = ldA(sp, ksl, half * 4 + q);
                #pragma unroll
                for (int q = 0; q < 4; ++q) {
                    int mq = half * 4 + q;
                    acc_r[mq] = mfma16(a[q], br1, acc_r[mq]);
                    acc_z[mq] = mfma16(a[q], bz1, acc_z[mq]);
                    accn[mq]  = mfma16(a[q], bn1, accn[mq]);
                    acc_r[mq] = mfma16(a[q], br2, acc_r[mq]);
                    acc_z[mq] = mfma16(a[q], bz2, acc_z[mq]);
                    accn[mq]  = mfma16(a[q], bn2, accn[mq]);
                }
            }
        }
    };
    auto consume_single = [&](int buf, const u16* b1, f32x4* accn) {
        const u16* sp = &As[buf][kh][0];
        #pragma unroll
        for (int ksl = 0; ksl < 2; ++ksl) {
            short8 br1 = *(const short8*)(b1 + ksl * 512);
            short8 bz1 = *(const short8*)(b1 + GS_ + ksl * 512);
            short8 bn1 = *(const short8*)(b1 + 2 * GS_ + ksl * 512);
            #pragma unroll
            for (int half = 0; half < 2; ++half) {
                short8 a[4];
                #pragma unroll
                for (int q = 0; q < 4; ++q) a[q] = ldA(sp, ksl, half * 4 + q);
                #pragma unroll
                for (int q = 0; q < 4; ++q) {
                    int mq = half * 4 + q;
                    acc_r[mq] = mfma16(a[q], br1, acc_r[mq]);
                    acc_z[mq] = mfma16(a[q], bz1, acc_z[mq]);
                    accn[mq]  = mfma16(a[q], bn1, accn[mq]);
                }
            }
        }
    };

    // ---- prologue: stage X1 into buf 0 ----
    stage_async(0, xb, xb + 64, XW_);
    // P0: X1 dual (w1x + w2x); prefetch X2
    __syncthreads();
    stage_async(1, xb + 128, xb + 192, XW_);
    consume_dual(0, wg + (2 * kh) * 512, wg + (4 + 2 * kh) * 512, acc_ni);
    // P1: X2 single (same w1x addresses, L2-hot); prefetch H1 i=0
    __syncthreads();
    stage_async(0, hb1, hb1 + 4 * 64, H_);
    consume_single(1, wg + (2 * kh) * 512, acc_ni);
    // P2: H1 i=0 dual; prefetch H1 i=1
    __syncthreads();
    stage_async(1, hb1 + 1 * 64, hb1 + 5 * 64, H_);
    consume_dual(0, wg + (8 + 8 * kh + 0) * 512, wg + (24 + 8 * kh + 0) * 512, acc_nh);
    // P3: H1 i=1 dual; prefetch H1 i=2
    __syncthreads();
    stage_async(0, hb1 + 2 * 64, hb1 + 6 * 64, H_);
    consume_dual(1, wg + (8 + 8 * kh + 2) * 512, wg + (24 + 8 * kh + 2) * 512, acc_nh);
    // P4: H1 i=2 dual; prefetch H1 i=3
    __syncthreads();
    stage_async(1, hb1 + 3 * 64, hb1 + 7 * 64, H_);
    consume_dual(0, wg + (8 + 8 * kh + 4) * 512, wg + (24 + 8 * kh + 4) * 512, acc_nh);
    // P5: H1 i=3 dual; prefetch H2 i=0
    __syncthreads();
    stage_async(0, hb2, hb2 + 4 * 64, H_);
    consume_dual(1, wg + (8 + 8 * kh + 6) * 512, wg + (24 + 8 * kh + 6) * 512, acc_nh);
    // P6: H2 i=0 single (same h-w1 addresses); prefetch H2 i=1
    __syncthreads();
    stage_async(1, hb2 + 1 * 64, hb2 + 5 * 64, H_);
    consume_single(0, wg + (8 + 8 * kh + 0) * 512, acc_nh);
    // P7: H2 i=1 single; prefetch H2 i=2
    __syncthreads();
    stage_async(0, hb2 + 2 * 64, hb2 + 6 * 64, H_);
    consume_single(1, wg + (8 + 8 * kh + 2) * 512, acc_nh);
    // P8: H2 i=2 single; prefetch H2 i=3
    __syncthreads();
    stage_async(1, hb2 + 3 * 64, hb2 + 7 * 64, H_);
    consume_single(0, wg + (8 + 8 * kh + 4) * 512, acc_nh);
    // P9: H2 i=3 single (no prefetch)
    __syncthreads();
    consume_single(1, wg + (8 + 8 * kh + 6) * 512, acc_nh);

    // ---- K-half reduction through LDS. rp spans 32 KB = As[0] exactly,
    // disjoint from As[1] that P9 stragglers still read. XOR entry swizzle.
    f32x4* rp = (f32x4*)As;
    const int rbase = (nh * 64 + lane) * 16;
    const int rxor  = lane & 7;
    if (kh == 1) {
        #pragma unroll
        for (int q = 0; q < 8; ++q) {
            rp[rbase + (q ^ rxor)]       = acc_r[q];
            rp[rbase + 8 + (q ^ rxor)]   = acc_z[q];
        }
    }
    __syncthreads();
    if (kh == 0) {
        #pragma unroll
        for (int q = 0; q < 8; ++q) {
            acc_r[q] += rp[rbase + (q ^ rxor)];
            acc_z[q] += rp[rbase + 8 + (q ^ rxor)];
        }
    }
    __syncthreads();
    if (kh == 1) {
        #pragma unroll
        for (int q = 0; q < 8; ++q) {
            rp[rbase + (q ^ rxor)]       = acc_ni[q];
            rp[rbase + 8 + (q ^ rxor)]   = acc_nh[q];
        }
    }
    __syncthreads();
    if (kh == 0) {
        #pragma unroll
        for (int q = 0; q < 8; ++q) {
            acc_ni[q] += rp[rbase + (q ^ rxor)];
            acc_nh[q] += rp[rbase + 8 + (q ^ rxor)];
        }

        // ---- GRU pointwise epilogue (f32), h reconstructed from bf16 pair --
        int hc = ht * 16 + l15;
        const float* bih = bp.bih[g];
        const float* bhh = bp.bhh[g];
        float b_ir = bih[hc],          b_hr = bhh[hc];
        float b_iz = bih[H_ + hc],     b_hz = bhh[H_ + hc];
        float b_in = bih[2 * H_ + hc], b_hn = bhh[2 * H_ + hc];
        #pragma unroll
        for (int mt = 0; mt < 8; ++mt) {
            #pragma unroll
            for (int i = 0; i < 4; ++i) {
                int m = m0 + mt * 16 + l4 * 4 + i;
                long idx = ((long)g * B_ + m) * H_ + hc;
                float pr = acc_r[mt][i] + b_ir + b_hr;
                float pz = acc_z[mt][i] + b_iz + b_hz;
                float vi = acc_ni[mt][i] + b_in;
                float vh = acc_nh[mt][i] + b_hn;
                float r = 1.f / (1.f + __expf(-pr));
                float z = 1.f / (1.f + __expf(-pz));
                float n = tanhf(vi + r * vh);
                float hold = bf2f(h1_in[idx]) + bf2f(h2_in[idx]);
                float hnew = (1.f - z) * n + z * hold;
                u16 hh = f2bf(hnew);
                h1_out[idx] = hh;
                h2_out[idx] = f2bf(hnew - bf2f(hh));
            }
        }
    }
}

// ---------- qc = 0.5*(eq+ec) from bf16 pairs, split into bf16 pair ----------
__global__ __launch_bounds__(256) void qc_kernel(
    const u16* __restrict__ h1, const u16* __restrict__ h2,
    u16* __restrict__ q1, u16* __restrict__ q2)
{
    int i = blockIdx.x * 256 + threadIdx.x;       // over 1024*512
    float eq = bf2f(h1[i]) + bf2f(h2[i]);
    float ec = bf2f(h1[B_ * H_ + i]) + bf2f(h2[B_ * H_ + i]);
    float q = 0.5f * (eq + ec);
    u16 h = f2bf(q);
    q1[i] = h;
    q2[i] = f2bf(q - bf2f(h));
}

// ---------- generic NT GEMM with per-chunk source pointers ------------------
struct GArgs { const u16* a[24]; const u16* b[24]; };

__global__ __launch_bounds__(256) void gemm_nt(
    GArgs ga, int nch, int astr, int bstr,
    const float* __restrict__ bias, float* __restrict__ outf,
    u16* __restrict__ ohi, u16* __restrict__ olo, int ldc, int mode)
{
    __shared__ __attribute__((aligned(16))) u16 As[64 * 72];
    __shared__ __attribute__((aligned(16))) u16 Bs[64 * 72];
    const int tid = threadIdx.x;
    const int w = tid >> 6, lane = tid & 63;
    const int l15 = lane & 15, l4 = lane >> 4;
    const int m0 = blockIdx.x * 64, n0 = blockIdx.y * 64;

    f32x4 zero = {0.f, 0.f, 0.f, 0.f};
    f32x4 acc[4] = {zero, zero, zero, zero};

    for (int c = 0; c < nch; ++c) {
        int row = tid >> 2, seg = tid & 3;
        const u16* sa = ga.a[c] + (long)(m0 + row) * astr + seg * 16;
        *(uint4*)(&As[row * 72 + seg * 16])     = *(const uint4*)(sa);
        *(uint4*)(&As[row * 72 + seg * 16 + 8]) = *(const uint4*)(sa + 8);
        const u16* sb = ga.b[c] + (long)(n0 + row) * bstr + seg * 16;
        *(uint4*)(&Bs[row * 72 + seg * 16])     = *(const uint4*)(sb);
        *(uint4*)(&Bs[row * 72 + seg * 16 + 8]) = *(const uint4*)(sb + 8);
        __syncthreads();
        #pragma unroll
        for (int ks = 0; ks < 2; ++ks) {
            short8 bfrag = *(const short8*)(&Bs[(w * 16 + l15) * 72 + ks * 32 + l4 * 8]);
            #pragma unroll
            for (int rt = 0; rt < 4; ++rt) {
                short8 a = *(const short8*)(&As[(rt * 16 + l15) * 72 + ks * 32 + l4 * 8]);
                acc[rt] = mfma16(a, bfrag, acc[rt]);
            }
        }
        __syncthreads();
    }

    int n = n0 + w * 16 + l15;
    float bv = bias ? bias[n] : 0.f;
    #pragma unroll
    for (int rt = 0; rt < 4; ++rt) {
        #pragma unroll
        for (int i = 0; i < 4; ++i) {
            int m = m0 + rt * 16 + l4 * 4 + i;
            float v = acc[rt][i] + bv;
            if (mode == 0) {
                outf[(long)m * ldc + n] = v;
            } else {
                u16 h = f2bf(v);
                ohi[(long)m * ldc + n] = h;
                olo[(long)m * ldc + n] = f2bf(v - bf2f(h));
            }
        }
    }
}

// ---------- row softmax (1024 wide), f32 in/out -----------------------------
__global__ __launch_bounds__(256) void softmax_kernel(
    const float* __restrict__ lg, float* __restrict__ out)
{
    __shared__ float red[256];
    int row = blockIdx.x, tid = threadIdx.x;
    const float* src = lg + (long)row * 1024;
    float x[4];
    float mx = -1e30f;
    #pragma unroll
    for (int i = 0; i < 4; ++i) { x[i] = src[tid + 256 * i]; mx = fmaxf(mx, x[i]); }
    red[tid] = mx; __syncthreads();
    for (int s = 128; s > 0; s >>= 1) { if (tid < s) red[tid] = fmaxf(red[tid], red[tid + s]); __syncthreads(); }
    mx = red[0]; __syncthreads();
    float sm = 0.f;
    #pragma unroll
    for (int i = 0; i < 4; ++i) { x[i] = __expf(x[i] - mx); sm += x[i]; }
    red[tid] = sm; __syncthreads();
    for (int s = 128; s > 0; s >>= 1) { if (tid < s) red[tid] += red[tid + s]; __syncthreads(); }
    float inv = 1.f / red[0];
    float* dst = out + (long)row * 1024;
    #pragma unroll
    for (int i = 0; i < 4; ++i) dst[tid + 256 * i] = x[i] * inv;
}

// ---------------------------------------------------------------------------
extern "C" void kernel_launch(void* const* d_in, const int* in_sizes, int n_in,
                              void* d_out, int out_size, void* d_ws, size_t ws_size,
                              hipStream_t stream)
{
    const int* tok[3] = {(const int*)d_in[0], (const int*)d_in[1], (const int*)d_in[2]};
    const float *emb[3], *wih[3], *whh[3], *bih[3], *bhh[3];
    for (int g = 0; g < 3; ++g) {
        emb[g] = (const float*)d_in[3 + 5 * g];
        wih[g] = (const float*)d_in[4 + 5 * g];
        whh[g] = (const float*)d_in[5 + 5 * g];
        bih[g] = (const float*)d_in[6 + 5 * g];
        bhh[g] = (const float*)d_in[7 + 5 * g];
    }
    const float* lin_w = (const float*)d_in[18];
    const float* lin_b = (const float*)d_in[19];

    char* ws = (char*)d_ws;
    size_t off = 0;
    auto alloc = [&](size_t bytes) { void* p = ws + off; off += (bytes + 255) & ~255ull; return p; };

    const size_t BH  = (size_t)B_ * H_;           // 524288
    const size_t PRB = 3 * BH * 2;                // bf16 plane bytes (3.1 MB)
    const size_t PING = 2 * PRB;                  // h1+h2 per ping

    u16*   Xs   = (u16*)alloc(3ll * S_ * B_ * XW_ * 2);     // 100.7 MB
    u16*   Wswz = (u16*)alloc(3ll * WSZG * 2);              // 11.8 MB
    u16*   LW1  = (u16*)alloc((size_t)H_ * H_ * 2);
    u16*   LW2  = (u16*)alloc((size_t)H_ * H_ * 2);
    char*  HB   = (char*)alloc(2 * PING);                   // 12.6 MB
    u16*   QC1  = (u16*)alloc(BH * 2);
    u16*   QC2  = (u16*)alloc(BH * 2);
    u16*   EQ1  = (u16*)alloc(BH * 2);
    u16*   EQ2  = (u16*)alloc(BH * 2);
    float* LG   = (float*)alloc(3ll * B_ * B_ * 4);         // 12.6 MB

    u16* H1[2]; u16* H2[2];
    for (int i = 0; i < 2; ++i) {
        char* pb = HB + (size_t)i * PING;
        H1[i] = (u16*)pb;
        H2[i] = (u16*)(pb + PRB);
    }

    hipMemsetAsync(HB, 0, PING, stream);   // zero h0 (ping 0: both planes)

    for (int g = 0; g < 3; ++g) {
        gather_kernel<<<dim3(S_ * B_ / 8), 256, 0, stream>>>(tok[g], emb[g], Xs + (size_t)g * S_ * B_ * XW_);
        repack_swz<<<dim3(WSZG / 256), 256, 0, stream>>>(wih[g], whh[g], Wswz + (size_t)g * WSZG);
    }
    repack_lin<<<dim3(H_ * H_ / 256), 256, 0, stream>>>(lin_w, LW1, LW2);

    BiasPtrs bp;
    for (int g = 0; g < 3; ++g) { bp.bih[g] = bih[g]; bp.bhh[g] = bhh[g]; }

    int p = 0;
    for (int t = S_ - 1; t >= 0; --t) {
        gru_step<<<dim3(16, 8, 3), 256, 0, stream>>>(Xs, Wswz, bp,
            H1[p], H2[p], H1[1 - p], H2[1 - p], t);
        p ^= 1;
    }
    const u16* H1F = H1[p];
    const u16* H2F = H2[p];

    qc_kernel<<<dim3(BH / 256), 256, 0, stream>>>(H1F, H2F, QC1, QC2);

    // eqc = qc @ lin_w.T + lin_b : q1w1 + q2w1 + q1w2 (24 chunks over K=512)
    GArgs ga;
    for (int c = 0; c < 8; ++c)   { ga.a[c] = QC1 + c * 64;        ga.b[c] = LW1 + c * 64; }
    for (int c = 8; c < 16; ++c)  { ga.a[c] = QC2 + (c - 8) * 64;  ga.b[c] = LW1 + (c - 8) * 64; }
    for (int c = 16; c < 24; ++c) { ga.a[c] = QC1 + (c - 16) * 64; ga.b[c] = LW2 + (c - 16) * 64; }
    gemm_nt<<<dim3(16, 8), 256, 0, stream>>>(ga, 24, H_, H_, lin_b, nullptr, EQ1, EQ2, H_, 1);

    // sims: logits = X @ er.T via a1b1 + a2b1 + a1b2
    const u16* R1 = H1F + 2 * BH;
    const u16* R2 = H2F + 2 * BH;
    for (int g = 0; g < 3; ++g) {
        const u16 *A1, *A2;
        if (g == 0)      { A1 = H1F;      A2 = H2F; }
        else if (g == 1) { A1 = H1F + BH; A2 = H2F + BH; }
        else             { A1 = EQ1;      A2 = EQ2; }
        GArgs gs;
        for (int c = 0; c < 8; ++c)   { gs.a[c] = A1 + c * 64;        gs.b[c] = R1 + c * 64; }
        for (int c = 8; c < 16; ++c)  { gs.a[c] = A2 + (c - 8) * 64;  gs.b[c] = R1 + (c - 8) * 64; }
        for (int c = 16; c < 24; ++c) { gs.a[c] = A1 + (c - 16) * 64; gs.b[c] = R2 + (c - 16) * 64; }
        gemm_nt<<<dim3(16, 16), 256, 0, stream>>>(gs, 24, H_, H_, nullptr,
            LG + (size_t)g * B_ * B_, nullptr, nullptr, B_, 0);
    }

    softmax_kernel<<<dim3(3 * B_), 256, 0, stream>>>(LG, (float*)d_out);
}

// Round 10
// 2203.204 us; speedup vs baseline: 1.3636x; 1.2279x over previous
//
#include <hip/hip_runtime.h>

typedef unsigned short u16;
typedef __attribute__((ext_vector_type(8))) short short8;
typedef __attribute__((ext_vector_type(4))) float f32x4;

#define B_   1024
#define S_   64
#define E_   100
#define H_   512
#define XW_  256      /* Xs row: x1[128] | x2[128] */
#define WSZG (32 * 3 * 40 * 512)   /* Wswz elems per encoder = 1,966,080 (dedup'd w1) */
#define GS_  (40 * 512)            /* gate stride inside Wswz */

typedef __attribute__((address_space(1))) const unsigned int gu32;
typedef __attribute__((address_space(3))) unsigned int lu32;

__device__ __forceinline__ float bf2f(u16 u) {
    union { unsigned int u; float f; } c; c.u = ((unsigned int)u) << 16; return c.f;
}
__device__ __forceinline__ u16 f2bf(float f) {
    union { float f; unsigned int u; } c; c.f = f;
    unsigned int r = c.u + 0x7fffu + ((c.u >> 16) & 1u);
    return (u16)(r >> 16);
}
__device__ __forceinline__ f32x4 mfma16(short8 a, short8 b, f32x4 c) {
    return __builtin_amdgcn_mfma_f32_16x16x32_bf16(a, b, c, 0, 0, 0);
}

// ---------- embedding gather -> bf16 hi/lo pair planes, zero-padded to 128 --
__global__ __launch_bounds__(256) void gather_kernel(
    const int* __restrict__ tok, const float* __restrict__ emb, u16* __restrict__ xs)
{
    int tid = threadIdx.x;
    int hw  = tid & 31;
    int rowid = blockIdx.x * 8 + (tid >> 5);      // rowid = t*1024 + b
    int t = rowid >> 10, b = rowid & 1023;
    int token = tok[b * S_ + t];
    const float* src = emb + (long)token * E_;
    u16* dst = xs + (long)rowid * XW_;
    int c0 = hw * 4;
    u16 a1[4], a2[4];
    #pragma unroll
    for (int j = 0; j < 4; ++j) {
        int c = c0 + j;
        float v = (c < E_) ? src[c] : 0.f;
        u16 h = f2bf(v);
        a1[j] = h;
        a2[j] = f2bf(v - bf2f(h));
    }
    uint2 p1, p2;
    p1.x = (unsigned)a1[0] | ((unsigned)a1[1] << 16);
    p1.y = (unsigned)a1[2] | ((unsigned)a1[3] << 16);
    p2.x = (unsigned)a2[0] | ((unsigned)a2[1] << 16);
    p2.y = (unsigned)a2[2] | ((unsigned)a2[3] << 16);
    *(uint2*)(dst + c0)       = p1;
    *(uint2*)(dst + 128 + c0) = p2;
}

// ---------- weight repack into MFMA-fragment order, w1 stored ONCE ----------
// Wswz[ht(32)][gate(3)][ks(40)][lane(64)][8] per encoder.
// ks 0-3: x w1 | ks 4-7: x w2 | ks 8-23: h w1 | ks 24-39: h w2.
__global__ __launch_bounds__(256) void repack_swz(
    const float* __restrict__ wih, const float* __restrict__ whh, u16* __restrict__ out)
{
    long idx = (long)blockIdx.x * 256 + threadIdx.x;   // over WSZG
    int jj   = idx & 7;
    int lane = (idx >> 3) & 63;
    int q9   = (int)(idx >> 9);
    int ks   = q9 % 40;
    int q    = q9 / 40;
    int gate = q % 3;
    int ht   = q / 3;
    int n   = ht * 16 + (lane & 15);
    int ck  = (lane >> 4) * 8 + jj;       // 0..31 within chunk
    int row = gate * H_ + n;
    float w; int lo;
    if (ks < 8) {
        int kk = (ks & 3) * 32 + ck;
        if (kk >= E_) { out[idx] = 0; return; }
        w = wih[row * E_ + kk];
        lo = (ks >> 2);                   // 0=hi(w1), 1=lo(w2)
    } else {
        int rel = ks - 8;
        int kk  = (rel & 15) * 32 + ck;
        w = whh[row * H_ + kk];
        lo = (rel >> 4);
    }
    u16 h = f2bf(w);
    if (lo) h = f2bf(w - bf2f(h));
    out[idx] = h;
}

__global__ __launch_bounds__(256) void repack_lin(
    const float* __restrict__ lw, u16* __restrict__ l1, u16* __restrict__ l2)
{
    int i = blockIdx.x * 256 + threadIdx.x;       // over 512*512
    float w = lw[i];
    u16 h = f2bf(w);
    l1[i] = h;
    l2[i] = f2bf(w - bf2f(h));
}

// ---------- one GRU time step ------------------------------------------------
// R14 = exact R4 champion (2120us: grid 16x16x3, 64-row m-blocks, flat h,
// gload_lds pipeline, XOR swizzle) + two small deltas:
//  (1) T14 on weights: pb[12] registers hold current phase's B-fragments;
//      MFMA cluster consumes pb, THEN issues next phase's B loads, which
//      land across the barrier (vmcnt-drained there). Removes the ~200-600cy
//      B-load latency from the top of every phase's critical path.
//  (2) K-half reduction in ONE 32KB round (post-P9 barrier makes all of As
//      free): 2 barriers instead of 3, half the LDS round-trips.
struct BiasPtrs { const float* bih[3]; const float* bhh[3]; };

__global__ __launch_bounds__(256, 3) void gru_step(
    const u16* __restrict__ xs,      // [3][64][1024][256]
    const u16* __restrict__ wswz,    // [3][WSZG]
    BiasPtrs bp,
    const u16* __restrict__ h1_in, const u16* __restrict__ h2_in,   // [3][1024][512]
    u16* __restrict__ h1_out, u16* __restrict__ h2_out,
    int t)
{
    __shared__ __attribute__((aligned(16))) u16 As[2][2][64 * 64];
    const int tid = threadIdx.x;
    const int lane = tid & 63;
    const int wid = tid >> 6;
    const int kh = tid >> 7;          // K-half  (0,1)
    const int nh = (tid >> 6) & 1;    // ht      (0,1)
    const int l15 = lane & 15, l4 = lane >> 4;
    const int htp = blockIdx.x;       // 0..15  (x-fastest => XCD-pinned weights)
    const int m0  = blockIdx.y * 64;
    const int g   = blockIdx.z;
    const int ht  = htp * 2 + nh;

    const u16* wg  = wswz + (long)g * WSZG + (long)ht * (3 * GS_) + lane * 8;
    const u16* xb  = xs + ((long)(g * S_ + t) * B_ + m0) * XW_;
    const u16* hb1 = h1_in + ((long)g * B_ + m0) * H_;
    const u16* hb2 = h2_in + ((long)g * B_ + m0) * H_;

    f32x4 zero = {0.f, 0.f, 0.f, 0.f};
    f32x4 acc_r[4]  = {zero, zero, zero, zero};
    f32x4 acc_z[4]  = {zero, zero, zero, zero};
    f32x4 acc_ni[4] = {zero, zero, zero, zero};
    f32x4 acc_nh[4] = {zero, zero, zero, zero};

    // persistent B-fragment registers (current phase's weights)
    short8 pb[12];
    auto loadB_dual = [&](const u16* b1, const u16* b2) {
        #pragma unroll
        for (int ksl = 0; ksl < 2; ++ksl) {
            pb[ksl * 6 + 0] = *(const short8*)(b1 + ksl * 512);
            pb[ksl * 6 + 1] = *(const short8*)(b1 + GS_ + ksl * 512);
            pb[ksl * 6 + 2] = *(const short8*)(b1 + 2 * GS_ + ksl * 512);
            pb[ksl * 6 + 3] = *(const short8*)(b2 + ksl * 512);
            pb[ksl * 6 + 4] = *(const short8*)(b2 + GS_ + ksl * 512);
            pb[ksl * 6 + 5] = *(const short8*)(b2 + 2 * GS_ + ksl * 512);
        }
    };
    auto loadB_single = [&](const u16* b1) {
        #pragma unroll
        for (int ksl = 0; ksl < 2; ++ksl) {
            pb[ksl * 6 + 0] = *(const short8*)(b1 + ksl * 512);
            pb[ksl * 6 + 1] = *(const short8*)(b1 + GS_ + ksl * 512);
            pb[ksl * 6 + 2] = *(const short8*)(b1 + 2 * GS_ + ksl * 512);
        }
    };

    // stage 16 KB: slot0 <- s0 tile, slot1 <- s1 tile (64 rows x 64 cols).
    auto stage_async = [&](int buf, const u16* s0, const u16* s1, int stride) {
        #pragma unroll
        for (int i = 0; i < 4; ++i) {
            int seg  = wid * 4 + i;            // 0..15
            int slot = seg >> 3;
            int rblk = seg & 7;
            const u16* src = slot ? s1 : s0;
            int row = rblk * 8 + (lane >> 3);
            int ch  = (lane & 7) ^ ((lane >> 3) & 7);
            const u16* gp = src + (long)row * stride + ch * 8;
            u16* lp = &As[buf][slot][rblk * 8 * 64];
            __builtin_amdgcn_global_load_lds((gu32*)gp, (lu32*)lp, 16, 0, 0);
        }
    };
    // swizzled A-fragment read: row r=q*16+l15, logical chunk ksl*4+l4
    auto ldA = [&](const u16* sp, int ksl, int q) -> short8 {
        int r = q * 16 + l15;
        int p = ((ksl << 2) + l4) ^ (l15 & 7);
        return *(const short8*)(&sp[r * 64 + p * 8]);
    };
    auto mfma_dual = [&](int buf, f32x4* accn) {
        const u16* sp = &As[buf][kh][0];
        #pragma unroll
        for (int ksl = 0; ksl < 2; ++ksl) {
            short8 a[4];
            #pragma unroll
            for (int q = 0; q < 4; ++q) a[q] = ldA(sp, ksl, q);
            #pragma unroll
            for (int q = 0; q < 4; ++q) {
                acc_r[q] = mfma16(a[q], pb[ksl * 6 + 0], acc_r[q]);
                acc_z[q] = mfma16(a[q], pb[ksl * 6 + 1], acc_z[q]);
                accn[q]  = mfma16(a[q], pb[ksl * 6 + 2], accn[q]);
                acc_r[q] = mfma16(a[q], pb[ksl * 6 + 3], acc_r[q]);
                acc_z[q] = mfma16(a[q], pb[ksl * 6 + 4], acc_z[q]);
                accn[q]  = mfma16(a[q], pb[ksl * 6 + 5], accn[q]);
            }
        }
    };
    auto mfma_single = [&](int buf, f32x4* accn) {
        const u16* sp = &As[buf][kh][0];
        #pragma unroll
        for (int ksl = 0; ksl < 2; ++ksl) {
            short8 a[4];
            #pragma unroll
            for (int q = 0; q < 4; ++q) a[q] = ldA(sp, ksl, q);
            #pragma unroll
            for (int q = 0; q < 4; ++q) {
                acc_r[q] = mfma16(a[q], pb[ksl * 6 + 0], acc_r[q]);
                acc_z[q] = mfma16(a[q], pb[ksl * 6 + 1], acc_z[q]);
                accn[q]  = mfma16(a[q], pb[ksl * 6 + 2], accn[q]);
            }
        }
    };

    // ---- prologue: stage X1 into buf 0; preload P0 weights ----
    stage_async(0, xb, xb + 64, XW_);
    loadB_dual(wg + (2 * kh) * 512, wg + (4 + 2 * kh) * 512);
    // P0: X1 dual; prefetch X2 + P1 weights
    __syncthreads();
    stage_async(1, xb + 128, xb + 192, XW_);
    mfma_dual(0, acc_ni);
    loadB_single(wg + (2 * kh) * 512);
    // P1: X2 single; prefetch H1 i=0 + P2 weights
    __syncthreads();
    stage_async(0, hb1, hb1 + 4 * 64, H_);
    mfma_single(1, acc_ni);
    loadB_dual(wg + (8 + 8 * kh + 0) * 512, wg + (24 + 8 * kh + 0) * 512);
    // P2: H1 i=0 dual; prefetch H1 i=1 + P3 weights
    __syncthreads();
    stage_async(1, hb1 + 1 * 64, hb1 + 5 * 64, H_);
    mfma_dual(0, acc_nh);
    loadB_dual(wg + (8 + 8 * kh + 2) * 512, wg + (24 + 8 * kh + 2) * 512);
    // P3: H1 i=1 dual; prefetch H1 i=2 + P4 weights
    __syncthreads();
    stage_async(0, hb1 + 2 * 64, hb1 + 6 * 64, H_);
    mfma_dual(1, acc_nh);
    loadB_dual(wg + (8 + 8 * kh + 4) * 512, wg + (24 + 8 * kh + 4) * 512);
    // P4: H1 i=2 dual; prefetch H1 i=3 + P5 weights
    __syncthreads();
    stage_async(1, hb1 + 3 * 64, hb1 + 7 * 64, H_);
    mfma_dual(0, acc_nh);
    loadB_dual(wg + (8 + 8 * kh + 6) * 512, wg + (24 + 8 * kh + 6) * 512);
    // P5: H1 i=3 dual; prefetch H2 i=0 + P6 weights
    __syncthreads();
    stage_async(0, hb2, hb2 + 4 * 64, H_);
    mfma_dual(1, acc_nh);
    loadB_single(wg + (8 + 8 * kh + 0) * 512);
    // P6: H2 i=0 single; prefetch H2 i=1 + P7 weights
    __syncthreads();
    stage_async(1, hb2 + 1 * 64, hb2 + 5 * 64, H_);
    mfma_single(0, acc_nh);
    loadB_single(wg + (8 + 8 * kh + 2) * 512);
    // P7: H2 i=1 single; prefetch H2 i=2 + P8 weights
    __syncthreads();
    stage_async(0, hb2 + 2 * 64, hb2 + 6 * 64, H_);
    mfma_single(1, acc_nh);
    loadB_single(wg + (8 + 8 * kh + 4) * 512);
    // P8: H2 i=2 single; prefetch H2 i=3 + P9 weights
    __syncthreads();
    stage_async(1, hb2 + 3 * 64, hb2 + 7 * 64, H_);
    mfma_single(0, acc_nh);
    loadB_single(wg + (8 + 8 * kh + 6) * 512);
    // P9: H2 i=3 single (no prefetch)
    __syncthreads();
    mfma_single(1, acc_nh);

    // ---- K-half reduction: ONE 32KB round (all of As free after barrier) ----
    __syncthreads();
    f32x4* rp = (f32x4*)As;
    const int rbase = (nh * 64 + lane) * 16;
    const int rxor  = lane & 7;
    if (kh == 1) {
        #pragma unroll
        for (int q = 0; q < 4; ++q) {
            rp[rbase + (q ^ rxor)]           = acc_r[q];
            rp[rbase + ((4 + q) ^ rxor)]     = acc_z[q];
            rp[rbase + 8 + (q ^ rxor)]       = acc_ni[q];
            rp[rbase + 8 + ((4 + q) ^ rxor)] = acc_nh[q];
        }
    }
    __syncthreads();
    if (kh == 0) {
        #pragma unroll
        for (int q = 0; q < 4; ++q) {
            acc_r[q]  += rp[rbase + (q ^ rxor)];
            acc_z[q]  += rp[rbase + ((4 + q) ^ rxor)];
            acc_ni[q] += rp[rbase + 8 + (q ^ rxor)];
            acc_nh[q] += rp[rbase + 8 + ((4 + q) ^ rxor)];
        }

        // ---- GRU pointwise epilogue (f32), h reconstructed from bf16 pair --
        int hc = ht * 16 + l15;
        const float* bih = bp.bih[g];
        const float* bhh = bp.bhh[g];
        float b_ir = bih[hc],          b_hr = bhh[hc];
        float b_iz = bih[H_ + hc],     b_hz = bhh[H_ + hc];
        float b_in = bih[2 * H_ + hc], b_hn = bhh[2 * H_ + hc];
        #pragma unroll
        for (int mt = 0; mt < 4; ++mt) {
            #pragma unroll
            for (int i = 0; i < 4; ++i) {
                int m = m0 + mt * 16 + l4 * 4 + i;
                long idx = ((long)g * B_ + m) * H_ + hc;
                float pr = acc_r[mt][i] + b_ir + b_hr;
                float pz = acc_z[mt][i] + b_iz + b_hz;
                float vi = acc_ni[mt][i] + b_in;
                float vh = acc_nh[mt][i] + b_hn;
                float r = 1.f / (1.f + __expf(-pr));
                float z = 1.f / (1.f + __expf(-pz));
                float n = tanhf(vi + r * vh);
                float hold = bf2f(h1_in[idx]) + bf2f(h2_in[idx]);
                float hnew = (1.f - z) * n + z * hold;
                u16 hh = f2bf(hnew);
                h1_out[idx] = hh;
                h2_out[idx] = f2bf(hnew - bf2f(hh));
            }
        }
    }
}

// ---------- qc = 0.5*(eq+ec) from bf16 pairs, split into bf16 pair ----------
__global__ __launch_bounds__(256) void qc_kernel(
    const u16* __restrict__ h1, const u16* __restrict__ h2,
    u16* __restrict__ q1, u16* __restrict__ q2)
{
    int i = blockIdx.x * 256 + threadIdx.x;       // over 1024*512
    float eq = bf2f(h1[i]) + bf2f(h2[i]);
    float ec = bf2f(h1[B_ * H_ + i]) + bf2f(h2[B_ * H_ + i]);
    float q = 0.5f * (eq + ec);
    u16 h = f2bf(q);
    q1[i] = h;
    q2[i] = f2bf(q - bf2f(h));
}

// ---------- generic NT GEMM with per-chunk source pointers ------------------
struct GArgs { const u16* a[24]; const u16* b[24]; };

__global__ __launch_bounds__(256) void gemm_nt(
    GArgs ga, int nch, int astr, int bstr,
    const float* __restrict__ bias, float* __restrict__ outf,
    u16* __restrict__ ohi, u16* __restrict__ olo, int ldc, int mode)
{
    __shared__ __attribute__((aligned(16))) u16 As[64 * 72];
    __shared__ __attribute__((aligned(16))) u16 Bs[64 * 72];
    const int tid = threadIdx.x;
    const int w = tid >> 6, lane = tid & 63;
    const int l15 = lane & 15, l4 = lane >> 4;
    const int m0 = blockIdx.x * 64, n0 = blockIdx.y * 64;

    f32x4 zero = {0.f, 0.f, 0.f, 0.f};
    f32x4 acc[4] = {zero, zero, zero, zero};

    for (int c = 0; c < nch; ++c) {
        int row = tid >> 2, seg = tid & 3;
        const u16* sa = ga.a[c] + (long)(m0 + row) * astr + seg * 16;
        *(uint4*)(&As[row * 72 + seg * 16])     = *(const uint4*)(sa);
        *(uint4*)(&As[row * 72 + seg * 16 + 8]) = *(const uint4*)(sa + 8);
        const u16* sb = ga.b[c] + (long)(n0 + row) * bstr + seg * 16;
        *(uint4*)(&Bs[row * 72 + seg * 16])     = *(const uint4*)(sb);
        *(uint4*)(&Bs[row * 72 + seg * 16 + 8]) = *(const uint4*)(sb + 8);
        __syncthreads();
        #pragma unroll
        for (int ks = 0; ks < 2; ++ks) {
            short8 bfrag = *(const short8*)(&Bs[(w * 16 + l15) * 72 + ks * 32 + l4 * 8]);
            #pragma unroll
            for (int rt = 0; rt < 4; ++rt) {
                short8 a = *(const short8*)(&As[(rt * 16 + l15) * 72 + ks * 32 + l4 * 8]);
                acc[rt] = mfma16(a, bfrag, acc[rt]);
            }
        }
        __syncthreads();
    }

    int n = n0 + w * 16 + l15;
    float bv = bias ? bias[n] : 0.f;
    #pragma unroll
    for (int rt = 0; rt < 4; ++rt) {
        #pragma unroll
        for (int i = 0; i < 4; ++i) {
            int m = m0 + rt * 16 + l4 * 4 + i;
            float v = acc[rt][i] + bv;
            if (mode == 0) {
                outf[(long)m * ldc + n] = v;
            } else {
                u16 h = f2bf(v);
                ohi[(long)m * ldc + n] = h;
                olo[(long)m * ldc + n] = f2bf(v - bf2f(h));
            }
        }
    }
}

// ---------- row softmax (1024 wide), f32 in/out -----------------------------
__global__ __launch_bounds__(256) void softmax_kernel(
    const float* __restrict__ lg, float* __restrict__ out)
{
    __shared__ float red[256];
    int row = blockIdx.x, tid = threadIdx.x;
    const float* src = lg + (long)row * 1024;
    float x[4];
    float mx = -1e30f;
    #pragma unroll
    for (int i = 0; i < 4; ++i) { x[i] = src[tid + 256 * i]; mx = fmaxf(mx, x[i]); }
    red[tid] = mx; __syncthreads();
    for (int s = 128; s > 0; s >>= 1) { if (tid < s) red[tid] = fmaxf(red[tid], red[tid + s]); __syncthreads(); }
    mx = red[0]; __syncthreads();
    float sm = 0.f;
    #pragma unroll
    for (int i = 0; i < 4; ++i) { x[i] = __expf(x[i] - mx); sm += x[i]; }
    red[tid] = sm; __syncthreads();
    for (int s = 128; s > 0; s >>= 1) { if (tid < s) red[tid] += red[tid + s]; __syncthreads(); }
    float inv = 1.f / red[0];
    float* dst = out + (long)row * 1024;
    #pragma unroll
    for (int i = 0; i < 4; ++i) dst[tid + 256 * i] = x[i] * inv;
}

// ---------------------------------------------------------------------------
extern "C" void kernel_launch(void* const* d_in, const int* in_sizes, int n_in,
                              void* d_out, int out_size, void* d_ws, size_t ws_size,
                              hipStream_t stream)
{
    const int* tok[3] = {(const int*)d_in[0], (const int*)d_in[1], (const int*)d_in[2]};
    const float *emb[3], *wih[3], *whh[3], *bih[3], *bhh[3];
    for (int g = 0; g < 3; ++g) {
        emb[g] = (const float*)d_in[3 + 5 * g];
        wih[g] = (const float*)d_in[4 + 5 * g];
        whh[g] = (const float*)d_in[5 + 5 * g];
        bih[g] = (const float*)d_in[6 + 5 * g];
        bhh[g] = (const float*)d_in[7 + 5 * g];
    }
    const float* lin_w = (const float*)d_in[18];
    const float* lin_b = (const float*)d_in[19];

    char* ws = (char*)d_ws;
    size_t off = 0;
    auto alloc = [&](size_t bytes) { void* p = ws + off; off += (bytes + 255) & ~255ull; return p; };

    const size_t BH  = (size_t)B_ * H_;           // 524288
    const size_t PRB = 3 * BH * 2;                // bf16 plane bytes (3.1 MB)
    const size_t PING = 2 * PRB;                  // h1+h2 per ping

    u16*   Xs   = (u16*)alloc(3ll * S_ * B_ * XW_ * 2);     // 100.7 MB
    u16*   Wswz = (u16*)alloc(3ll * WSZG * 2);              // 11.8 MB
    u16*   LW1  = (u16*)alloc((size_t)H_ * H_ * 2);
    u16*   LW2  = (u16*)alloc((size_t)H_ * H_ * 2);
    char*  HB   = (char*)alloc(2 * PING);                   // 12.6 MB
    u16*   QC1  = (u16*)alloc(BH * 2);
    u16*   QC2  = (u16*)alloc(BH * 2);
    u16*   EQ1  = (u16*)alloc(BH * 2);
    u16*   EQ2  = (u16*)alloc(BH * 2);
    float* LG   = (float*)alloc(3ll * B_ * B_ * 4);         // 12.6 MB

    u16* H1[2]; u16* H2[2];
    for (int i = 0; i < 2; ++i) {
        char* pb = HB + (size_t)i * PING;
        H1[i] = (u16*)pb;
        H2[i] = (u16*)(pb + PRB);
    }

    hipMemsetAsync(HB, 0, PING, stream);   // zero h0 (ping 0: both planes)

    for (int g = 0; g < 3; ++g) {
        gather_kernel<<<dim3(S_ * B_ / 8), 256, 0, stream>>>(tok[g], emb[g], Xs + (size_t)g * S_ * B_ * XW_);
        repack_swz<<<dim3(WSZG / 256), 256, 0, stream>>>(wih[g], whh[g], Wswz + (size_t)g * WSZG);
    }
    repack_lin<<<dim3(H_ * H_ / 256), 256, 0, stream>>>(lin_w, LW1, LW2);

    BiasPtrs bp;
    for (int g = 0; g < 3; ++g) { bp.bih[g] = bih[g]; bp.bhh[g] = bhh[g]; }

    int p = 0;
    for (int t = S_ - 1; t >= 0; --t) {
        gru_step<<<dim3(16, 16, 3), 256, 0, stream>>>(Xs, Wswz, bp,
            H1[p], H2[p], H1[1 - p], H2[1 - p], t);
        p ^= 1;
    }
    const u16* H1F = H1[p];
    const u16* H2F = H2[p];

    qc_kernel<<<dim3(BH / 256), 256, 0, stream>>>(H1F, H2F, QC1, QC2);

    // eqc = qc @ lin_w.T + lin_b : q1w1 + q2w1 + q1w2 (24 chunks over K=512)
    GArgs ga;
    for (int c = 0; c < 8; ++c)   { ga.a[c] = QC1 + c * 64;        ga.b[c] = LW1 + c * 64; }
    for (int c = 8; c < 16; ++c)  { ga.a[c] = QC2 + (c - 8) * 64;  ga.b[c] = LW1 + (c - 8) * 64; }
    for (int c = 16; c < 24; ++c) { ga.a[c] = QC1 + (c - 16) * 64; ga.b[c] = LW2 + (c - 16) * 64; }
    gemm_nt<<<dim3(16, 8), 256, 0, stream>>>(ga, 24, H_, H_, lin_b, nullptr, EQ1, EQ2, H_, 1);

    // sims: logits = X @ er.T via a1b1 + a2b1 + a1b2
    const u16* R1 = H1F + 2 * BH;
    const u16* R2 = H2F + 2 * BH;
    for (int g = 0; g < 3; ++g) {
        const u16 *A1, *A2;
        if (g == 0)      { A1 = H1F;      A2 = H2F; }
        else if (g == 1) { A1 = H1F + BH; A2 = H2F + BH; }
        else             { A1 = EQ1;      A2 = EQ2; }
        GArgs gs;
        for (int c = 0; c < 8; ++c)   { gs.a[c] = A1 + c * 64;        gs.b[c] = R1 + c * 64; }
        for (int c = 8; c < 16; ++c)  { gs.a[c] = A2 + (c - 8) * 64;  gs.b[c] = R1 + (c - 8) * 64; }
        for (int c = 16; c < 24; ++c) { gs.a[c] = A1 + (c - 16) * 64; gs.b[c] = R2 + (c - 16) * 64; }
        gemm_nt<<<dim3(16, 16), 256, 0, stream>>>(gs, 24, H_, H_, nullptr,
            LG + (size_t)g * B_ * B_, nullptr, nullptr, B_, 0);
    }

    softmax_kernel<<<dim3(3 * B_), 256, 0, stream>>>(LG, (float*)d_out);
}

// Round 12
// 2028.808 us; speedup vs baseline: 1.4808x; 1.0860x over previous
//
#include <hip/hip_runtime.h>

typedef unsigned short u16;
typedef __attribute__((ext_vector_type(8))) short short8;
typedef __attribute__((ext_vector_type(4))) float f32x4;

#define B_   1024
#define S_   64
#define E_   100
#define H_   512
#define XW_  256      /* Xs row: x1[128] | x2[128] */
#define WSZG (32 * 3 * 40 * 512)   /* Wswz elems per encoder = 1,966,080 (dedup'd w1) */
#define GS_  (40 * 512)            /* gate stride inside Wswz */

typedef __attribute__((address_space(1))) const unsigned int gu32;
typedef __attribute__((address_space(3))) unsigned int lu32;

__device__ __forceinline__ float bf2f(u16 u) {
    union { unsigned int u; float f; } c; c.u = ((unsigned int)u) << 16; return c.f;
}
__device__ __forceinline__ u16 f2bf(float f) {
    union { float f; unsigned int u; } c; c.f = f;
    unsigned int r = c.u + 0x7fffu + ((c.u >> 16) & 1u);
    return (u16)(r >> 16);
}
__device__ __forceinline__ f32x4 mfma16(short8 a, short8 b, f32x4 c) {
    return __builtin_amdgcn_mfma_f32_16x16x32_bf16(a, b, c, 0, 0, 0);
}

// ---------- embedding gather -> bf16 hi/lo pair planes, zero-padded to 128 --
__global__ __launch_bounds__(256) void gather_kernel(
    const int* __restrict__ tok, const float* __restrict__ emb, u16* __restrict__ xs)
{
    int tid = threadIdx.x;
    int hw  = tid & 31;
    int rowid = blockIdx.x * 8 + (tid >> 5);      // rowid = t*1024 + b
    int t = rowid >> 10, b = rowid & 1023;
    int token = tok[b * S_ + t];
    const float* src = emb + (long)token * E_;
    u16* dst = xs + (long)rowid * XW_;
    int c0 = hw * 4;
    u16 a1[4], a2[4];
    #pragma unroll
    for (int j = 0; j < 4; ++j) {
        int c = c0 + j;
        float v = (c < E_) ? src[c] : 0.f;
        u16 h = f2bf(v);
        a1[j] = h;
        a2[j] = f2bf(v - bf2f(h));
    }
    uint2 p1, p2;
    p1.x = (unsigned)a1[0] | ((unsigned)a1[1] << 16);
    p1.y = (unsigned)a1[2] | ((unsigned)a1[3] << 16);
    p2.x = (unsigned)a2[0] | ((unsigned)a2[1] << 16);
    p2.y = (unsigned)a2[2] | ((unsigned)a2[3] << 16);
    *(uint2*)(dst + c0)       = p1;
    *(uint2*)(dst + 128 + c0) = p2;
}

// ---------- weight repack into MFMA-fragment order, w1 stored ONCE ----------
// Wswz[ht(32)][gate(3)][ks(40)][lane(64)][8] per encoder.
// ks 0-3: x w1 | ks 4-7: x w2 | ks 8-23: h w1 | ks 24-39: h w2.
__global__ __launch_bounds__(256) void repack_swz(
    const float* __restrict__ wih, const float* __restrict__ whh, u16* __restrict__ out)
{
    long idx = (long)blockIdx.x * 256 + threadIdx.x;   // over WSZG
    int jj   = idx & 7;
    int lane = (idx >> 3) & 63;
    int q9   = (int)(idx >> 9);
    int ks   = q9 % 40;
    int q    = q9 / 40;
    int gate = q % 3;
    int ht   = q / 3;
    int n   = ht * 16 + (lane & 15);
    int ck  = (lane >> 4) * 8 + jj;       // 0..31 within chunk
    int row = gate * H_ + n;
    float w; int lo;
    if (ks < 8) {
        int kk = (ks & 3) * 32 + ck;
        if (kk >= E_) { out[idx] = 0; return; }
        w = wih[row * E_ + kk];
        lo = (ks >> 2);                   // 0=hi(w1), 1=lo(w2)
    } else {
        int rel = ks - 8;
        int kk  = (rel & 15) * 32 + ck;
        w = whh[row * H_ + kk];
        lo = (rel >> 4);
    }
    u16 h = f2bf(w);
    if (lo) h = f2bf(w - bf2f(h));
    out[idx] = h;
}

__global__ __launch_bounds__(256) void repack_lin(
    const float* __restrict__ lw, u16* __restrict__ l1, u16* __restrict__ l2)
{
    int i = blockIdx.x * 256 + threadIdx.x;       // over 512*512
    float w = lw[i];
    u16 h = f2bf(w);
    l1[i] = h;
    l2[i] = f2bf(w - bf2f(h));
}

// ---------- one GRU time step ------------------------------------------------
// R15 = byte-identical R4 champion body (2120us), with ONLY the block-index
// decode changed to a 2D XCD decomposition: xcd = blockIdx.x % 8 encodes
// (hq = weight quarter, mh = batch half). Each XCD now needs weights for
// 8 ht columns (2.95 MB, L2-resident) and h/x for only HALF the batch
// (3.15 MB h + 0.8 MB x per step) -> the per-step cross-XCD h broadcast
// halves: ~50 -> ~27 MB/step of L3 fetch.
struct BiasPtrs { const float* bih[3]; const float* bhh[3]; };

__global__ __launch_bounds__(256, 3) void gru_step(
    const u16* __restrict__ xs,      // [3][64][1024][256]
    const u16* __restrict__ wswz,    // [3][WSZG]
    BiasPtrs bp,
    const u16* __restrict__ h1_in, const u16* __restrict__ h2_in,   // [3][1024][512]
    u16* __restrict__ h1_out, u16* __restrict__ h2_out,
    int t)
{
    __shared__ __attribute__((aligned(16))) u16 As[2][2][64 * 64];
    const int tid = threadIdx.x;
    const int lane = tid & 63;
    const int wid = tid >> 6;
    const int kh = tid >> 7;          // K-half  (0,1)
    const int nh = (tid >> 6) & 1;    // ht      (0,1)
    const int l15 = lane & 15, l4 = lane >> 4;
    // --- 2D XCD decode: xcd = bx%8 = hq*2 + mh ---
    const int bx   = blockIdx.x;              // 0..127
    const int hq   = (bx & 7) >> 1;           // weight quarter 0..3
    const int mh   = bx & 1;                  // batch half 0..1
    const int rest = bx >> 3;                 // 0..15
    const int htp  = hq * 4 + (rest & 3);     // 0..15
    const int mi   = mh * 8 + (rest >> 2) + blockIdx.y * 4;   // 0..15
    const int m0   = mi * 64;
    const int g    = blockIdx.z;
    const int ht   = htp * 2 + nh;

    const u16* wg  = wswz + (long)g * WSZG + (long)ht * (3 * GS_) + lane * 8;
    const u16* xb  = xs + ((long)(g * S_ + t) * B_ + m0) * XW_;
    const u16* hb1 = h1_in + ((long)g * B_ + m0) * H_;
    const u16* hb2 = h2_in + ((long)g * B_ + m0) * H_;

    f32x4 zero = {0.f, 0.f, 0.f, 0.f};
    f32x4 acc_r[4]  = {zero, zero, zero, zero};
    f32x4 acc_z[4]  = {zero, zero, zero, zero};
    f32x4 acc_ni[4] = {zero, zero, zero, zero};
    f32x4 acc_nh[4] = {zero, zero, zero, zero};

    // stage 16 KB: slot0 <- s0 tile, slot1 <- s1 tile (64 rows x 64 cols).
    auto stage_async = [&](int buf, const u16* s0, const u16* s1, int stride) {
        #pragma unroll
        for (int i = 0; i < 4; ++i) {
            int seg  = wid * 4 + i;            // 0..15
            int slot = seg >> 3;
            int rblk = seg & 7;
            const u16* src = slot ? s1 : s0;
            int row = rblk * 8 + (lane >> 3);
            int ch  = (lane & 7) ^ ((lane >> 3) & 7);
            const u16* gp = src + (long)row * stride + ch * 8;
            u16* lp = &As[buf][slot][rblk * 8 * 64];
            __builtin_amdgcn_global_load_lds((gu32*)gp, (lu32*)lp, 16, 0, 0);
        }
    };
    // swizzled A-fragment read: row r=q*16+l15, logical chunk ksl*4+l4
    auto ldA = [&](const u16* sp, int ksl, int q) -> short8 {
        int r = q * 16 + l15;
        int p = ((ksl << 2) + l4) ^ (l15 & 7);
        return *(const short8*)(&sp[r * 64 + p * 8]);
    };
    auto consume_dual = [&](int buf, const u16* b1, const u16* b2, f32x4* accn) {
        const u16* sp = &As[buf][kh][0];
        #pragma unroll
        for (int ksl = 0; ksl < 2; ++ksl) {
            short8 br1 = *(const short8*)(b1 + ksl * 512);
            short8 bz1 = *(const short8*)(b1 + GS_ + ksl * 512);
            short8 bn1 = *(const short8*)(b1 + 2 * GS_ + ksl * 512);
            short8 br2 = *(const short8*)(b2 + ksl * 512);
            short8 bz2 = *(const short8*)(b2 + GS_ + ksl * 512);
            short8 bn2 = *(const short8*)(b2 + 2 * GS_ + ksl * 512);
            short8 a[4];
            #pragma unroll
            for (int q = 0; q < 4; ++q) a[q] = ldA(sp, ksl, q);
            #pragma unroll
            for (int q = 0; q < 4; ++q) {
                acc_r[q] = mfma16(a[q], br1, acc_r[q]);
                acc_z[q] = mfma16(a[q], bz1, acc_z[q]);
                accn[q]  = mfma16(a[q], bn1, accn[q]);
                acc_r[q] = mfma16(a[q], br2, acc_r[q]);
                acc_z[q] = mfma16(a[q], bz2, acc_z[q]);
                accn[q]  = mfma16(a[q], bn2, accn[q]);
            }
        }
    };
    auto consume_single = [&](int buf, const u16* b1, f32x4* accn) {
        const u16* sp = &As[buf][kh][0];
        #pragma unroll
        for (int ksl = 0; ksl < 2; ++ksl) {
            short8 br1 = *(const short8*)(b1 + ksl * 512);
            short8 bz1 = *(const short8*)(b1 + GS_ + ksl * 512);
            short8 bn1 = *(const short8*)(b1 + 2 * GS_ + ksl * 512);
            short8 a[4];
            #pragma unroll
            for (int q = 0; q < 4; ++q) a[q] = ldA(sp, ksl, q);
            #pragma unroll
            for (int q = 0; q < 4; ++q) {
                acc_r[q] = mfma16(a[q], br1, acc_r[q]);
                acc_z[q] = mfma16(a[q], bz1, acc_z[q]);
                accn[q]  = mfma16(a[q], bn1, accn[q]);
            }
        }
    };

    // ---- prologue: stage X1 into buf 0 ----
    stage_async(0, xb, xb + 64, XW_);
    // P0: X1 dual (w1x + w2x); prefetch X2
    __syncthreads();
    stage_async(1, xb + 128, xb + 192, XW_);
    consume_dual(0, wg + (2 * kh) * 512, wg + (4 + 2 * kh) * 512, acc_ni);
    // P1: X2 single (same w1x addresses, L2-hot); prefetch H1 i=0
    __syncthreads();
    stage_async(0, hb1, hb1 + 4 * 64, H_);
    consume_single(1, wg + (2 * kh) * 512, acc_ni);
    // P2: H1 i=0 dual; prefetch H1 i=1
    __syncthreads();
    stage_async(1, hb1 + 1 * 64, hb1 + 5 * 64, H_);
    consume_dual(0, wg + (8 + 8 * kh + 0) * 512, wg + (24 + 8 * kh + 0) * 512, acc_nh);
    // P3: H1 i=1 dual; prefetch H1 i=2
    __syncthreads();
    stage_async(0, hb1 + 2 * 64, hb1 + 6 * 64, H_);
    consume_dual(1, wg + (8 + 8 * kh + 2) * 512, wg + (24 + 8 * kh + 2) * 512, acc_nh);
    // P4: H1 i=2 dual; prefetch H1 i=3
    __syncthreads();
    stage_async(1, hb1 + 3 * 64, hb1 + 7 * 64, H_);
    consume_dual(0, wg + (8 + 8 * kh + 4) * 512, wg + (24 + 8 * kh + 4) * 512, acc_nh);
    // P5: H1 i=3 dual; prefetch H2 i=0
    __syncthreads();
    stage_async(0, hb2, hb2 + 4 * 64, H_);
    consume_dual(1, wg + (8 + 8 * kh + 6) * 512, wg + (24 + 8 * kh + 6) * 512, acc_nh);
    // P6: H2 i=0 single (same h-w1 addresses); prefetch H2 i=1
    __syncthreads();
    stage_async(1, hb2 + 1 * 64, hb2 + 5 * 64, H_);
    consume_single(0, wg + (8 + 8 * kh + 0) * 512, acc_nh);
    // P7: H2 i=1 single; prefetch H2 i=2
    __syncthreads();
    stage_async(0, hb2 + 2 * 64, hb2 + 6 * 64, H_);
    consume_single(1, wg + (8 + 8 * kh + 2) * 512, acc_nh);
    // P8: H2 i=2 single; prefetch H2 i=3
    __syncthreads();
    stage_async(1, hb2 + 3 * 64, hb2 + 7 * 64, H_);
    consume_single(0, wg + (8 + 8 * kh + 4) * 512, acc_nh);
    // P9: H2 i=3 single (no prefetch)
    __syncthreads();
    consume_single(1, wg + (8 + 8 * kh + 6) * 512, acc_nh);

    // ---- K-half reduction through LDS (first 16 KB = As[0], disjoint from
    // As[1] that P9 stragglers still read). XOR chunk swizzle: conflict-free.
    f32x4* rp = (f32x4*)As;
    const int rbase = (nh * 64 + lane) * 8;
    const int rxor  = lane & 7;
    if (kh == 1) {
        #pragma unroll
        for (int q = 0; q < 4; ++q) {
            rp[rbase + (q ^ rxor)]       = acc_r[q];
            rp[rbase + ((4 + q) ^ rxor)] = acc_z[q];
        }
    }
    __syncthreads();
    if (kh == 0) {
        #pragma unroll
        for (int q = 0; q < 4; ++q) {
            acc_r[q] += rp[rbase + (q ^ rxor)];
            acc_z[q] += rp[rbase + ((4 + q) ^ rxor)];
        }
    }
    __syncthreads();
    if (kh == 1) {
        #pragma unroll
        for (int q = 0; q < 4; ++q) {
            rp[rbase + (q ^ rxor)]       = acc_ni[q];
            rp[rbase + ((4 + q) ^ rxor)] = acc_nh[q];
        }
    }
    __syncthreads();
    if (kh == 0) {
        #pragma unroll
        for (int q = 0; q < 4; ++q) {
            acc_ni[q] += rp[rbase + (q ^ rxor)];
            acc_nh[q] += rp[rbase + ((4 + q) ^ rxor)];
        }

        // ---- GRU pointwise epilogue (f32), h reconstructed from bf16 pair --
        int hc = ht * 16 + l15;
        const float* bih = bp.bih[g];
        const float* bhh = bp.bhh[g];
        float b_ir = bih[hc],          b_hr = bhh[hc];
        float b_iz = bih[H_ + hc],     b_hz = bhh[H_ + hc];
        float b_in = bih[2 * H_ + hc], b_hn = bhh[2 * H_ + hc];
        #pragma unroll
        for (int mt = 0; mt < 4; ++mt) {
            #pragma unroll
            for (int i = 0; i < 4; ++i) {
                int m = m0 + mt * 16 + l4 * 4 + i;
                long idx = ((long)g * B_ + m) * H_ + hc;
                float pr = acc_r[mt][i] + b_ir + b_hr;
                float pz = acc_z[mt][i] + b_iz + b_hz;
                float vi = acc_ni[mt][i] + b_in;
                float vh = acc_nh[mt][i] + b_hn;
                float r = 1.f / (1.f + __expf(-pr));
                float z = 1.f / (1.f + __expf(-pz));
                float n = tanhf(vi + r * vh);
                float hold = bf2f(h1_in[idx]) + bf2f(h2_in[idx]);
                float hnew = (1.f - z) * n + z * hold;
                u16 hh = f2bf(hnew);
                h1_out[idx] = hh;
                h2_out[idx] = f2bf(hnew - bf2f(hh));
            }
        }
    }
}

// ---------- qc = 0.5*(eq+ec) from bf16 pairs, split into bf16 pair ----------
__global__ __launch_bounds__(256) void qc_kernel(
    const u16* __restrict__ h1, const u16* __restrict__ h2,
    u16* __restrict__ q1, u16* __restrict__ q2)
{
    int i = blockIdx.x * 256 + threadIdx.x;       // over 1024*512
    float eq = bf2f(h1[i]) + bf2f(h2[i]);
    float ec = bf2f(h1[B_ * H_ + i]) + bf2f(h2[B_ * H_ + i]);
    float q = 0.5f * (eq + ec);
    u16 h = f2bf(q);
    q1[i] = h;
    q2[i] = f2bf(q - bf2f(h));
}

// ---------- generic NT GEMM with per-chunk source pointers ------------------
struct GArgs { const u16* a[24]; const u16* b[24]; };

__global__ __launch_bounds__(256) void gemm_nt(
    GArgs ga, int nch, int astr, int bstr,
    const float* __restrict__ bias, float* __restrict__ outf,
    u16* __restrict__ ohi, u16* __restrict__ olo, int ldc, int mode)
{
    __shared__ __attribute__((aligned(16))) u16 As[64 * 72];
    __shared__ __attribute__((aligned(16))) u16 Bs[64 * 72];
    const int tid = threadIdx.x;
    const int w = tid >> 6, lane = tid & 63;
    const int l15 = lane & 15, l4 = lane >> 4;
    const int m0 = blockIdx.x * 64, n0 = blockIdx.y * 64;

    f32x4 zero = {0.f, 0.f, 0.f, 0.f};
    f32x4 acc[4] = {zero, zero, zero, zero};

    for (int c = 0; c < nch; ++c) {
        int row = tid >> 2, seg = tid & 3;
        const u16* sa = ga.a[c] + (long)(m0 + row) * astr + seg * 16;
        *(uint4*)(&As[row * 72 + seg * 16])     = *(const uint4*)(sa);
        *(uint4*)(&As[row * 72 + seg * 16 + 8]) = *(const uint4*)(sa + 8);
        const u16* sb = ga.b[c] + (long)(n0 + row) * bstr + seg * 16;
        *(uint4*)(&Bs[row * 72 + seg * 16])     = *(const uint4*)(sb);
        *(uint4*)(&Bs[row * 72 + seg * 16 + 8]) = *(const uint4*)(sb + 8);
        __syncthreads();
        #pragma unroll
        for (int ks = 0; ks < 2; ++ks) {
            short8 bfrag = *(const short8*)(&Bs[(w * 16 + l15) * 72 + ks * 32 + l4 * 8]);
            #pragma unroll
            for (int rt = 0; rt < 4; ++rt) {
                short8 a = *(const short8*)(&As[(rt * 16 + l15) * 72 + ks * 32 + l4 * 8]);
                acc[rt] = mfma16(a, bfrag, acc[rt]);
            }
        }
        __syncthreads();
    }

    int n = n0 + w * 16 + l15;
    float bv = bias ? bias[n] : 0.f;
    #pragma unroll
    for (int rt = 0; rt < 4; ++rt) {
        #pragma unroll
        for (int i = 0; i < 4; ++i) {
            int m = m0 + rt * 16 + l4 * 4 + i;
            float v = acc[rt][i] + bv;
            if (mode == 0) {
                outf[(long)m * ldc + n] = v;
            } else {
                u16 h = f2bf(v);
                ohi[(long)m * ldc + n] = h;
                olo[(long)m * ldc + n] = f2bf(v - bf2f(h));
            }
        }
    }
}

// ---------- row softmax (1024 wide), f32 in/out -----------------------------
__global__ __launch_bounds__(256) void softmax_kernel(
    const float* __restrict__ lg, float* __restrict__ out)
{
    __shared__ float red[256];
    int row = blockIdx.x, tid = threadIdx.x;
    const float* src = lg + (long)row * 1024;
    float x[4];
    float mx = -1e30f;
    #pragma unroll
    for (int i = 0; i < 4; ++i) { x[i] = src[tid + 256 * i]; mx = fmaxf(mx, x[i]); }
    red[tid] = mx; __syncthreads();
    for (int s = 128; s > 0; s >>= 1) { if (tid < s) red[tid] = fmaxf(red[tid], red[tid + s]); __syncthreads(); }
    mx = red[0]; __syncthreads();
    float sm = 0.f;
    #pragma unroll
    for (int i = 0; i < 4; ++i) { x[i] = __expf(x[i] - mx); sm += x[i]; }
    red[tid] = sm; __syncthreads();
    for (int s = 128; s > 0; s >>= 1) { if (tid < s) red[tid] += red[tid + s]; __syncthreads(); }
    float inv = 1.f / red[0];
    float* dst = out + (long)row * 1024;
    #pragma unroll
    for (int i = 0; i < 4; ++i) dst[tid + 256 * i] = x[i] * inv;
}

// ---------------------------------------------------------------------------
extern "C" void kernel_launch(void* const* d_in, const int* in_sizes, int n_in,
                              void* d_out, int out_size, void* d_ws, size_t ws_size,
                              hipStream_t stream)
{
    const int* tok[3] = {(const int*)d_in[0], (const int*)d_in[1], (const int*)d_in[2]};
    const float *emb[3], *wih[3], *whh[3], *bih[3], *bhh[3];
    for (int g = 0; g < 3; ++g) {
        emb[g] = (const float*)d_in[3 + 5 * g];
        wih[g] = (const float*)d_in[4 + 5 * g];
        whh[g] = (const float*)d_in[5 + 5 * g];
        bih[g] = (const float*)d_in[6 + 5 * g];
        bhh[g] = (const float*)d_in[7 + 5 * g];
    }
    const float* lin_w = (const float*)d_in[18];
    const float* lin_b = (const float*)d_in[19];

    char* ws = (char*)d_ws;
    size_t off = 0;
    auto alloc = [&](size_t bytes) { void* p = ws + off; off += (bytes + 255) & ~255ull; return p; };

    const size_t BH  = (size_t)B_ * H_;           // 524288
    const size_t PRB = 3 * BH * 2;                // bf16 plane bytes (3.1 MB)
    const size_t PING = 2 * PRB;                  // h1+h2 per ping

    u16*   Xs   = (u16*)alloc(3ll * S_ * B_ * XW_ * 2);     // 100.7 MB
    u16*   Wswz = (u16*)alloc(3ll * WSZG * 2);              // 11.8 MB
    u16*   LW1  = (u16*)alloc((size_t)H_ * H_ * 2);
    u16*   LW2  = (u16*)alloc((size_t)H_ * H_ * 2);
    char*  HB   = (char*)alloc(2 * PING);                   // 12.6 MB
    u16*   QC1  = (u16*)alloc(BH * 2);
    u16*   QC2  = (u16*)alloc(BH * 2);
    u16*   EQ1  = (u16*)alloc(BH * 2);
    u16*   EQ2  = (u16*)alloc(BH * 2);
    float* LG   = (float*)alloc(3ll * B_ * B_ * 4);         // 12.6 MB

    u16* H1[2]; u16* H2[2];
    for (int i = 0; i < 2; ++i) {
        char* pb = HB + (size_t)i * PING;
        H1[i] = (u16*)pb;
        H2[i] = (u16*)(pb + PRB);
    }

    hipMemsetAsync(HB, 0, PING, stream);   // zero h0 (ping 0: both planes)

    for (int g = 0; g < 3; ++g) {
        gather_kernel<<<dim3(S_ * B_ / 8), 256, 0, stream>>>(tok[g], emb[g], Xs + (size_t)g * S_ * B_ * XW_);
        repack_swz<<<dim3(WSZG / 256), 256, 0, stream>>>(wih[g], whh[g], Wswz + (size_t)g * WSZG);
    }
    repack_lin<<<dim3(H_ * H_ / 256), 256, 0, stream>>>(lin_w, LW1, LW2);

    BiasPtrs bp;
    for (int g = 0; g < 3; ++g) { bp.bih[g] = bih[g]; bp.bhh[g] = bhh[g]; }

    int p = 0;
    for (int t = S_ - 1; t >= 0; --t) {
        gru_step<<<dim3(128, 2, 3), 256, 0, stream>>>(Xs, Wswz, bp,
            H1[p], H2[p], H1[1 - p], H2[1 - p], t);
        p ^= 1;
    }
    const u16* H1F = H1[p];
    const u16* H2F = H2[p];

    qc_kernel<<<dim3(BH / 256), 256, 0, stream>>>(H1F, H2F, QC1, QC2);

    // eqc = qc @ lin_w.T + lin_b : q1w1 + q2w1 + q1w2 (24 chunks over K=512)
    GArgs ga;
    for (int c = 0; c < 8; ++c)   { ga.a[c] = QC1 + c * 64;        ga.b[c] = LW1 + c * 64; }
    for (int c = 8; c < 16; ++c)  { ga.a[c] = QC2 + (c - 8) * 64;  ga.b[c] = LW1 + (c - 8) * 64; }
    for (int c = 16; c < 24; ++c) { ga.a[c] = QC1 + (c - 16) * 64; ga.b[c] = LW2 + (c - 16) * 64; }
    gemm_nt<<<dim3(16, 8), 256, 0, stream>>>(ga, 24, H_, H_, lin_b, nullptr, EQ1, EQ2, H_, 1);

    // sims: logits = X @ er.T via a1b1 + a2b1 + a1b2
    const u16* R1 = H1F + 2 * BH;
    const u16* R2 = H2F + 2 * BH;
    for (int g = 0; g < 3; ++g) {
        const u16 *A1, *A2;
        if (g == 0)      { A1 = H1F;      A2 = H2F; }
        else if (g == 1) { A1 = H1F + BH; A2 = H2F + BH; }
        else             { A1 = EQ1;      A2 = EQ2; }
        GArgs gs;
        for (int c = 0; c < 8; ++c)   { gs.a[c] = A1 + c * 64;        gs.b[c] = R1 + c * 64; }
        for (int c = 8; c < 16; ++c)  { gs.a[c] = A2 + (c - 8) * 64;  gs.b[c] = R1 + (c - 8) * 64; }
        for (int c = 16; c < 24; ++c) { gs.a[c] = A1 + (c - 16) * 64; gs.b[c] = R2 + (c - 16) * 64; }
        gemm_nt<<<dim3(16, 16), 256, 0, stream>>>(gs, 24, H_, H_, nullptr,
            LG + (size_t)g * B_ * B_, nullptr, nullptr, B_, 0);
    }

    softmax_kernel<<<dim3(3 * B_), 256, 0, stream>>>(LG, (float*)d_out);
}